// Round 1
// baseline (802.496 us; speedup 1.0000x reference)
//
#include <hip/hip_runtime.h>
#include <stdint.h>

typedef unsigned short u16;
typedef __bf16 bf16x8 __attribute__((ext_vector_type(8)));
typedef float  f32x4 __attribute__((ext_vector_type(4)));
typedef u16    u16x8 __attribute__((ext_vector_type(8)));
typedef u16    u16x4 __attribute__((ext_vector_type(4)));

constexpr int LL = 512;
constexpr int NROW = LL * LL;   // 262144 flat rows (i*L+k or i*L+j)

__device__ __forceinline__ u16 f2b(float f) {
    __bf16 h = (__bf16)f;                 // RNE; compiler pairs into v_cvt_pk_bf16_f32
    return __builtin_bit_cast(u16, h);
}
__device__ __forceinline__ float b2f(u16 s) {
    union { unsigned u; float f; } v; v.u = ((unsigned)s) << 16; return v.f;
}
__device__ __forceinline__ float sigmoidf_(float x) { return 1.0f / (1.0f + __expf(-x)); }

__device__ __forceinline__ f32x4 mfma16(bf16x8 a, bf16x8 b, f32x4 c) {
    return __builtin_amdgcn_mfma_f32_16x16x32_bf16(a, b, c, 0, 0, 0);
}

// ---------------- Kernel 0: weights f32 -> bf16 (one-time, tiny) ----------------
__global__ __launch_bounds__(256)
void k0_wconv(const float* __restrict__ Wap, const float* __restrict__ Wag,
              const float* __restrict__ Wbp, const float* __restrict__ Wbg,
              const float* __restrict__ Wg, const float* __restrict__ Wo,
              u16* __restrict__ wbf)
{
    const float* srcs[6] = {Wap, Wag, Wbp, Wbg, Wg, Wo};
    const int m = blockIdx.x >> 6;                       // 64 blocks per 16384-elem matrix
    const int e = ((blockIdx.x & 63) << 8) | threadIdx.x;
    wbf[m * 16384 + e] = f2b(srcs[m][e]);
}

// ---------------- Kernel 1: LN(z) + 5 projections ----------------
// z f32 [NROW][128]. LN two-pass from global (tile re-read hits L1/L2).
// a_t,b_t bf16 channel-major [c][NROW] via direct u16x4 stores; gate f32 -> d_out.
// nt-split: only 64 accumulator regs live at once -> 4 blocks/CU residency.
__global__ __launch_bounds__(256, 4)
void k1_ln_proj(const float* __restrict__ z, const float* __restrict__ mask,
                const float* __restrict__ lg, const float* __restrict__ lb,
                const u16* __restrict__ Wapb, const float* __restrict__ bap,
                const u16* __restrict__ Wagb, const float* __restrict__ bag,
                const u16* __restrict__ Wbpb, const float* __restrict__ bbp,
                const u16* __restrict__ Wbgb, const float* __restrict__ bbg,
                const u16* __restrict__ Wgb, const float* __restrict__ bgv,
                u16* __restrict__ a_t, u16* __restrict__ b_t, float* __restrict__ gate)
{
    __shared__ __align__(16) u16 Zs[128][136];  // z_norm bf16 tile; stride 272 B
    __shared__ float Gg[128], Gb[128], Ms[128];

    const int tid = threadIdx.x;
    const int row0 = blockIdx.x * 128;

    if (tid < 128) { Gg[tid] = lg[tid]; Gb[tid] = lb[tid]; Ms[tid] = mask[row0 + tid]; }

    // ---- LN phase: pair (2r,2r+1) owns row r; halves h=0/64 ----
    const int r = tid >> 1, h = (tid & 1) * 64;
    const float* zrow = z + (size_t)(row0 + r) * 128 + h;
    float s1 = 0.f, s2 = 0.f;
#pragma unroll
    for (int j = 0; j < 64; j += 4) {
        f32x4 v = *(const f32x4*)(zrow + j);
#pragma unroll
        for (int e = 0; e < 4; ++e) { s1 += v[e]; s2 += v[e] * v[e]; }
    }
    s1 += __shfl_xor(s1, 1);
    s2 += __shfl_xor(s2, 1);
    const float mu = s1 * 0.0078125f;
    const float rs = rsqrtf(fmaxf(s2 * 0.0078125f - mu * mu, 0.f) + 1e-5f);
    __syncthreads();  // Gg/Gb ready
#pragma unroll
    for (int j = 0; j < 64; j += 4) {
        f32x4 v = *(const f32x4*)(zrow + j);  // re-read, L1/L2 hot
        u16x4 o;
#pragma unroll
        for (int e = 0; e < 4; ++e)
            o[e] = f2b((v[e] - mu) * rs * Gg[h + j + e] + Gb[h + j + e]);
        *(u16x4*)&Zs[r][h + j] = o;
    }
    __syncthreads();

    const int lane = tid & 63, wave = tid >> 6;
    const int wm = (wave >> 1) * 64, wn = (wave & 1) * 64;
    const int lr = lane & 15, quad = lane >> 4, kq = quad * 8;

    // ---- a/b projections: P * sigmoid(G), masked, bf16 channel-major out ----
    // Split over nt halves so accP+accG = 64 regs live (not 128): register file
    // (unified VGPR+AGPR on gfx950) was capping residency at 2 blocks/CU.
#pragma unroll 1
    for (int pair = 0; pair < 2; ++pair) {
        const u16* WP = pair ? Wbpb : Wapb;
        const float* BP = pair ? bbp : bap;
        const u16* WG = pair ? Wbgb : Wagb;
        const float* BG = pair ? bbg : bag;
        u16* outp = pair ? b_t : a_t;

#pragma unroll 1
        for (int nh = 0; nh < 2; ++nh) {
            f32x4 accP[4][2], accG[4][2];
#pragma unroll
            for (int i = 0; i < 4; ++i)
#pragma unroll
                for (int j = 0; j < 2; ++j) {
                    accP[i][j] = (f32x4){0.f, 0.f, 0.f, 0.f};
                    accG[i][j] = (f32x4){0.f, 0.f, 0.f, 0.f};
                }
#pragma unroll
            for (int kk = 0; kk < 128; kk += 32) {
                bf16x8 af[4];
#pragma unroll
                for (int mt = 0; mt < 4; ++mt)
                    af[mt] = *(const bf16x8*)&Zs[wm + mt * 16 + lr][kk + kq];
#pragma unroll
                for (int n2 = 0; n2 < 2; ++n2) {
                    const int ncol = wn + (nh * 2 + n2) * 16 + lr;
                    bf16x8 bp8 = *(const bf16x8*)(WP + ncol * 128 + kk + kq);
                    bf16x8 bg8 = *(const bf16x8*)(WG + ncol * 128 + kk + kq);
#pragma unroll
                    for (int mt = 0; mt < 4; ++mt) {
                        accP[mt][n2] = mfma16(af[mt], bp8, accP[mt][n2]);
                        accG[mt][n2] = mfma16(af[mt], bg8, accG[mt][n2]);
                    }
                }
            }
            // C/D layout: col=lane&15 (=ncol), row=quad*4+e -> rows contiguous in [c][row]
#pragma unroll
            for (int n2 = 0; n2 < 2; ++n2) {
                const int ncol = wn + (nh * 2 + n2) * 16 + lr;
                const float bP = BP[ncol];
                const float bG = BG[ncol];
#pragma unroll
                for (int mt = 0; mt < 4; ++mt) {
                    const int rb = wm + mt * 16 + quad * 4;
                    u16x4 o;
#pragma unroll
                    for (int e = 0; e < 4; ++e)
                        o[e] = f2b((accP[mt][n2][e] + bP) * sigmoidf_(accG[mt][n2][e] + bG) * Ms[rb + e]);
                    *(u16x4*)(outp + (size_t)ncol * NROW + row0 + rb) = o;
                }
            }
        }
    }

    // ---- gate = sigmoid(z_norm @ Wg^T + bg), f32, natural layout into d_out ----
    {
        f32x4 acc[4][4];
#pragma unroll
        for (int i = 0; i < 4; ++i)
#pragma unroll
            for (int j = 0; j < 4; ++j) acc[i][j] = (f32x4){0.f, 0.f, 0.f, 0.f};
#pragma unroll
        for (int kk = 0; kk < 128; kk += 32) {
            bf16x8 af[4];
#pragma unroll
            for (int mt = 0; mt < 4; ++mt)
                af[mt] = *(const bf16x8*)&Zs[wm + mt * 16 + lr][kk + kq];
#pragma unroll
            for (int nt = 0; nt < 4; ++nt) {
                bf16x8 bw = *(const bf16x8*)(Wgb + (wn + nt * 16 + lr) * 128 + kk + kq);
#pragma unroll
                for (int mt = 0; mt < 4; ++mt) acc[mt][nt] = mfma16(af[mt], bw, acc[mt][nt]);
            }
        }
#pragma unroll
        for (int nt = 0; nt < 4; ++nt) {
            const int ncol = wn + nt * 16 + lr;
            const float bb = bgv[ncol];
#pragma unroll
            for (int mt = 0; mt < 4; ++mt) {
                const int rb = wm + mt * 16 + quad * 4;
#pragma unroll
                for (int e = 0; e < 4; ++e)
                    gate[(size_t)(row0 + rb + e) * 128 + ncol] = sigmoidf_(acc[mt][nt][e] + bb);
            }
        }
    }
}

// ---------------- Kernel 2: scale[i,j] = rsqrt(max(mask_i . mask_j, 1)) ----------------
__global__ __launch_bounds__(256, 2)
void k2_scale(const float* __restrict__ mask, float* __restrict__ scale)
{
    __shared__ __align__(16) u16 As[128][72];
    __shared__ __align__(16) u16 Bs[128][72];

    const int tid = threadIdx.x;
    const int i0 = (blockIdx.x >> 2) * 128, j0 = (blockIdx.x & 3) * 128;
    const int lane = tid & 63, wave = tid >> 6;
    const int wm = (wave >> 1) * 64, wn = (wave & 1) * 64;
    const int lr = lane & 15, quad = lane >> 4, kq = quad * 8;

    f32x4 acc[4][4];
#pragma unroll
    for (int i = 0; i < 4; ++i)
#pragma unroll
        for (int j = 0; j < 4; ++j) acc[i][j] = (f32x4){0.f, 0.f, 0.f, 0.f};

    for (int kc = 0; kc < LL; kc += 64) {
#pragma unroll
        for (int p = 0; p < 8; ++p) {
            const int q = p * 256 + tid, rr = q >> 4, ko = (q & 15) * 4;
            f32x4 va = *(const f32x4*)(mask + (size_t)(i0 + rr) * LL + kc + ko);
            f32x4 vb = *(const f32x4*)(mask + (size_t)(j0 + rr) * LL + kc + ko);
            u16x4 ca, cb;
#pragma unroll
            for (int e = 0; e < 4; ++e) { ca[e] = f2b(va[e]); cb[e] = f2b(vb[e]); }
            *(u16x4*)&As[rr][ko] = ca;
            *(u16x4*)&Bs[rr][ko] = cb;
        }
        __syncthreads();
#pragma unroll
        for (int kk = 0; kk < 64; kk += 32) {
            bf16x8 af[4], bf[4];
#pragma unroll
            for (int mt = 0; mt < 4; ++mt) af[mt] = *(const bf16x8*)&As[wm + mt * 16 + lr][kk + kq];
#pragma unroll
            for (int nt = 0; nt < 4; ++nt) bf[nt] = *(const bf16x8*)&Bs[wn + nt * 16 + lr][kk + kq];
#pragma unroll
            for (int mt = 0; mt < 4; ++mt)
#pragma unroll
                for (int nt = 0; nt < 4; ++nt) acc[mt][nt] = mfma16(af[mt], bf[nt], acc[mt][nt]);
        }
        __syncthreads();
    }
#pragma unroll
    for (int mt = 0; mt < 4; ++mt)
#pragma unroll
        for (int nt = 0; nt < 4; ++nt) {
            const int gj = j0 + wn + nt * 16 + lr;
#pragma unroll
            for (int e = 0; e < 4; ++e) {
                const int gi = i0 + wm + mt * 16 + quad * 4 + e;
                scale[(size_t)gi * LL + gj] = rsqrtf(fmaxf(acc[mt][nt][e], 1.0f));
            }
        }
}

// ---------------- Kernel 3: triangle einsum, per-channel C = A.B^T ----------------
// grid 2048 = 8 XCDs x (16 channels x 16 tiles); a channel's 16 tiles share one XCD's L2.
__global__ __launch_bounds__(256, 4)
void k3_einsum(const u16* __restrict__ a_t, const u16* __restrict__ b_t,
               const float* __restrict__ scale, u16* __restrict__ x_t)
{
    __shared__ __align__(16) u16 pool[2 * 128 * 72];  // As|Bs, reused as Ss post-K-loop
    u16 (*As)[72] = (u16(*)[72])pool;
    u16 (*Bs)[72] = (u16(*)[72])(pool + 128 * 72);
    u16 (*Ss)[128] = (u16(*)[128])pool;

    const int bid = blockIdx.x;
    const int xcd = bid & 7, slot = bid >> 3;
    const int c = xcd * 16 + (slot >> 4);
    const int tile = slot & 15;
    const int i0 = (tile >> 2) * 128, j0 = (tile & 3) * 128;

    const u16* A = a_t + (size_t)c * NROW;
    const u16* B = b_t + (size_t)c * NROW;

    const int tid = threadIdx.x;
    const int lane = tid & 63, wave = tid >> 6;
    const int wm = (wave >> 1) * 64, wn = (wave & 1) * 64;
    const int lr = lane & 15, quad = lane >> 4, kq = quad * 8;

    f32x4 acc[4][4];
#pragma unroll
    for (int i = 0; i < 4; ++i)
#pragma unroll
        for (int j = 0; j < 4; ++j) acc[i][j] = (f32x4){0.f, 0.f, 0.f, 0.f};

    for (int kc = 0; kc < LL; kc += 64) {
#pragma unroll
        for (int p = 0; p < 4; ++p) {
            const int q = p * 256 + tid, rr = q >> 3, ko = (q & 7) * 8;
            *(u16x8*)&As[rr][ko] = *(const u16x8*)(A + (size_t)(i0 + rr) * LL + kc + ko);
            *(u16x8*)&Bs[rr][ko] = *(const u16x8*)(B + (size_t)(j0 + rr) * LL + kc + ko);
        }
        __syncthreads();
#pragma unroll
        for (int kk = 0; kk < 64; kk += 32) {
            bf16x8 af[4], bf[4];
#pragma unroll
            for (int mt = 0; mt < 4; ++mt) af[mt] = *(const bf16x8*)&As[wm + mt * 16 + lr][kk + kq];
#pragma unroll
            for (int nt = 0; nt < 4; ++nt) bf[nt] = *(const bf16x8*)&Bs[wn + nt * 16 + lr][kk + kq];
#pragma unroll
            for (int mt = 0; mt < 4; ++mt)
#pragma unroll
                for (int nt = 0; nt < 4; ++nt) acc[mt][nt] = mfma16(af[mt], bf[nt], acc[mt][nt]);
        }
        __syncthreads();  // also guards pool reuse below on last iteration
    }
    // epilogue: x = acc * scale[i,j] -> bf16, stash (pool reuse) then coalesced store
#pragma unroll
    for (int mt = 0; mt < 4; ++mt)
#pragma unroll
        for (int nt = 0; nt < 4; ++nt) {
            const int cc = wn + nt * 16 + lr;
#pragma unroll
            for (int e = 0; e < 4; ++e) {
                const int rr = wm + mt * 16 + quad * 4 + e;
                const float s = scale[(size_t)(i0 + rr) * LL + j0 + cc];
                Ss[rr][cc] = f2b(acc[mt][nt][e] * s);
            }
        }
    __syncthreads();
#pragma unroll
    for (int p = 0; p < 8; ++p) {
        const int rr = p * 16 + (tid >> 4);
        const int jo = (tid & 15) * 8;
        *(u16x8*)(x_t + (size_t)c * NROW + (size_t)(i0 + rr) * LL + j0 + jo) = *(const u16x8*)&Ss[rr][jo];
    }
}

// ---------------- Kernel 4: LN(x) @ Wo^T + bo, * gate * mask ----------------
// gate/out both alias d_out f32: each lane reads gate[idx] then writes out[idx]
// at the SAME address (per-lane ordered, no cross-thread hazard).
__global__ __launch_bounds__(256, 4)
void k4_out(const u16* __restrict__ x_t, const float* __restrict__ mask,
            const float* __restrict__ lg, const float* __restrict__ lb,
            const u16* __restrict__ Wob, const float* __restrict__ bo,
            const float* gate, float* out)
{
    __shared__ __align__(16) u16 Zs[128][136];  // x_norm bf16 tile
    __shared__ float Ms[128];

    const int tid = threadIdx.x;
    const int row0 = blockIdx.x * 128;

    if (tid < 128) Ms[tid] = mask[row0 + tid];

    {   // transpose-stage x_t[c][ij] -> Zs[ij][c] via in-register 4x4 transpose
        const int ijo = (tid & 31) * 4;
        const int cb = (tid >> 5) * 4;
#pragma unroll
        for (int p = 0; p < 4; ++p) {
            const int c = p * 32 + cb;
            u16x4 v0 = *(const u16x4*)(x_t + (size_t)(c + 0) * NROW + row0 + ijo);
            u16x4 v1 = *(const u16x4*)(x_t + (size_t)(c + 1) * NROW + row0 + ijo);
            u16x4 v2 = *(const u16x4*)(x_t + (size_t)(c + 2) * NROW + row0 + ijo);
            u16x4 v3 = *(const u16x4*)(x_t + (size_t)(c + 3) * NROW + row0 + ijo);
#pragma unroll
            for (int i = 0; i < 4; ++i) {
                u16x4 w = { v0[i], v1[i], v2[i], v3[i] };
                *(u16x4*)&Zs[ijo + i][c] = w;
            }
        }
    }
    __syncthreads();

    // in-place LN over rows of Zs (bf16 -> f32 stats -> bf16)
    {
        const int r = tid >> 1, h = (tid & 1) * 64;
        float s1 = 0.f, s2 = 0.f;
#pragma unroll
        for (int j = 0; j < 64; j += 8) {
            u16x8 v = *(const u16x8*)&Zs[r][h + j];
#pragma unroll
            for (int e = 0; e < 8; ++e) { float x = b2f(v[e]); s1 += x; s2 += x * x; }
        }
        s1 += __shfl_xor(s1, 1);
        s2 += __shfl_xor(s2, 1);
        const float mu = s1 * 0.0078125f;
        const float rs = rsqrtf(fmaxf(s2 * 0.0078125f - mu * mu, 0.f) + 1e-5f);
#pragma unroll
        for (int j = 0; j < 64; j += 8) {
            const int c = h + j;
            u16x8 v = *(const u16x8*)&Zs[r][c];
            u16x8 o;
#pragma unroll
            for (int e = 0; e < 8; ++e)
                o[e] = f2b((b2f(v[e]) - mu) * rs * lg[c + e] + lb[c + e]);
            *(u16x8*)&Zs[r][c] = o;
        }
    }
    __syncthreads();

    const int lane = tid & 63, wave = tid >> 6;
    const int wm = (wave >> 1) * 64, wn = (wave & 1) * 64;
    const int lr = lane & 15, quad = lane >> 4, kq = quad * 8;

    f32x4 acc[4][4];
#pragma unroll
    for (int i = 0; i < 4; ++i)
#pragma unroll
        for (int j = 0; j < 4; ++j) acc[i][j] = (f32x4){0.f, 0.f, 0.f, 0.f};

#pragma unroll
    for (int kk = 0; kk < 128; kk += 32) {
        bf16x8 af[4];
#pragma unroll
        for (int mt = 0; mt < 4; ++mt)
            af[mt] = *(const bf16x8*)&Zs[wm + mt * 16 + lr][kk + kq];
#pragma unroll
        for (int nt = 0; nt < 4; ++nt) {
            bf16x8 bw = *(const bf16x8*)(Wob + (wn + nt * 16 + lr) * 128 + kk + kq);
#pragma unroll
            for (int mt = 0; mt < 4; ++mt) acc[mt][nt] = mfma16(af[mt], bw, acc[mt][nt]);
        }
    }
#pragma unroll
    for (int nt = 0; nt < 4; ++nt) {
        const int cc = wn + nt * 16 + lr;
        const float bb = bo[cc];
#pragma unroll
        for (int mt = 0; mt < 4; ++mt) {
            const int rb = wm + mt * 16 + quad * 4;
#pragma unroll
            for (int e = 0; e < 4; ++e) {
                const size_t idx = (size_t)(row0 + rb + e) * 128 + cc;
                const float g = gate[idx];           // read own element
                out[idx] = (acc[mt][nt][e] + bb) * g * Ms[rb + e];  // then overwrite it
            }
        }
    }
}

// ---------------- launcher ----------------
// ws: a_t 64MiB + b_t 64MiB + x_t 64MiB + wbf 192KiB + scale 1MiB ~= 193.2 MiB.
// gate lives in d_out (f32), k4 reads-then-writes the same addresses per lane.
extern "C" void kernel_launch(void* const* d_in, const int* in_sizes, int n_in,
                              void* d_out, int out_size, void* d_ws, size_t ws_size,
                              hipStream_t stream)
{
    const float* z        = (const float*)d_in[0];
    const float* mask     = (const float*)d_in[1];
    const float* ln_in_g  = (const float*)d_in[2];
    const float* ln_in_b  = (const float*)d_in[3];
    const float* Wap      = (const float*)d_in[4];
    const float* bap      = (const float*)d_in[5];
    const float* Wbp      = (const float*)d_in[6];
    const float* bbp      = (const float*)d_in[7];
    const float* Wag      = (const float*)d_in[8];
    const float* bag      = (const float*)d_in[9];
    const float* Wbg      = (const float*)d_in[10];
    const float* bbg      = (const float*)d_in[11];
    const float* ln_out_g = (const float*)d_in[12];
    const float* ln_out_b = (const float*)d_in[13];
    const float* Wo       = (const float*)d_in[14];
    const float* bo       = (const float*)d_in[15];
    const float* Wg       = (const float*)d_in[16];
    const float* bg       = (const float*)d_in[17];

    u16* a_t = (u16*)d_ws;
    u16* b_t = a_t + (size_t)128 * NROW;
    u16* x_t = b_t + (size_t)128 * NROW;
    u16* wbf = x_t + (size_t)128 * NROW;         // 6 x 16384 bf16 weights
    float* scale = (float*)(wbf + 6 * 16384);    // byte offset is 16-aligned
    float* gate = (float*)d_out;
    float* out  = (float*)d_out;

    const u16* Wapb = wbf + 0 * 16384;
    const u16* Wagb = wbf + 1 * 16384;
    const u16* Wbpb = wbf + 2 * 16384;
    const u16* Wbgb = wbf + 3 * 16384;
    const u16* Wgb  = wbf + 4 * 16384;
    const u16* Wob  = wbf + 5 * 16384;

    k0_wconv<<<dim3(384), dim3(256), 0, stream>>>(Wap, Wag, Wbp, Wbg, Wg, Wo, wbf);
    k1_ln_proj<<<dim3(2048), dim3(256), 0, stream>>>(z, mask, ln_in_g, ln_in_b,
        Wapb, bap, Wagb, bag, Wbpb, bbp, Wbgb, bbg, Wgb, bg, a_t, b_t, gate);
    k2_scale<<<dim3(16), dim3(256), 0, stream>>>(mask, scale);
    k3_einsum<<<dim3(2048), dim3(256), 0, stream>>>(a_t, b_t, scale, x_t);
    k4_out<<<dim3(2048), dim3(256), 0, stream>>>(x_t, mask, ln_out_g, ln_out_b, Wob, bo, gate, out);
}

// Round 2
// 777.670 us; speedup vs baseline: 1.0319x; 1.0319x over previous
//
#include <hip/hip_runtime.h>
#include <stdint.h>

typedef unsigned short u16;
typedef __bf16 bf16x8 __attribute__((ext_vector_type(8)));
typedef float  f32x4 __attribute__((ext_vector_type(4)));
typedef u16    u16x8 __attribute__((ext_vector_type(8)));
typedef u16    u16x4 __attribute__((ext_vector_type(4)));

constexpr int LL = 512;
constexpr int NROW = LL * LL;   // 262144 flat rows (i*L+k or i*L+j)

__device__ __forceinline__ u16 f2b(float f) {
    __bf16 h = (__bf16)f;                 // RNE; compiler pairs into v_cvt_pk_bf16_f32
    return __builtin_bit_cast(u16, h);
}
__device__ __forceinline__ float b2f(u16 s) {
    union { unsigned u; float f; } v; v.u = ((unsigned)s) << 16; return v.f;
}
__device__ __forceinline__ float sigmoidf_(float x) { return 1.0f / (1.0f + __expf(-x)); }

__device__ __forceinline__ f32x4 mfma16(bf16x8 a, bf16x8 b, f32x4 c) {
    return __builtin_amdgcn_mfma_f32_16x16x32_bf16(a, b, c, 0, 0, 0);
}

// ---------------- Kernel 0: weights f32 -> bf16 (one-time, tiny) ----------------
__global__ __launch_bounds__(256)
void k0_wconv(const float* __restrict__ Wap, const float* __restrict__ Wag,
              const float* __restrict__ Wbp, const float* __restrict__ Wbg,
              const float* __restrict__ Wg, const float* __restrict__ Wo,
              u16* __restrict__ wbf)
{
    const float* srcs[6] = {Wap, Wag, Wbp, Wbg, Wg, Wo};
    const int m = blockIdx.x >> 6;                       // 64 blocks per 16384-elem matrix
    const int e = ((blockIdx.x & 63) << 8) | threadIdx.x;
    wbf[m * 16384 + e] = f2b(srcs[m][e]);
}

// ---------------- Kernel 1: LN(z) + 5 projections ----------------
// z f32 [NROW][128]. LN two-pass from global (tile re-read hits L1/L2).
// a_t,b_t bf16 channel-major [c][NROW] via direct u16x4 stores; gate f32 -> d_out.
// nt-split keeps live accs at 64; (256,3) gives a 170-reg unified budget
// (NO spill — (256,4)'s 128-reg budget spilled, +660MB scratch traffic, r1).
__global__ __launch_bounds__(256, 3)
void k1_ln_proj(const float* __restrict__ z, const float* __restrict__ mask,
                const float* __restrict__ lg, const float* __restrict__ lb,
                const u16* __restrict__ Wapb, const float* __restrict__ bap,
                const u16* __restrict__ Wagb, const float* __restrict__ bag,
                const u16* __restrict__ Wbpb, const float* __restrict__ bbp,
                const u16* __restrict__ Wbgb, const float* __restrict__ bbg,
                const u16* __restrict__ Wgb, const float* __restrict__ bgv,
                u16* __restrict__ a_t, u16* __restrict__ b_t, float* __restrict__ gate)
{
    __shared__ __align__(16) u16 Zs[128][136];  // z_norm bf16 tile; stride 272 B
    __shared__ float Gg[128], Gb[128], Ms[128];

    const int tid = threadIdx.x;
    const int row0 = blockIdx.x * 128;

    if (tid < 128) { Gg[tid] = lg[tid]; Gb[tid] = lb[tid]; Ms[tid] = mask[row0 + tid]; }

    // ---- LN phase: pair (2r,2r+1) owns row r; halves h=0/64 ----
    const int r = tid >> 1, h = (tid & 1) * 64;
    const float* zrow = z + (size_t)(row0 + r) * 128 + h;
    float s1 = 0.f, s2 = 0.f;
#pragma unroll
    for (int j = 0; j < 64; j += 4) {
        f32x4 v = *(const f32x4*)(zrow + j);
#pragma unroll
        for (int e = 0; e < 4; ++e) { s1 += v[e]; s2 += v[e] * v[e]; }
    }
    s1 += __shfl_xor(s1, 1);
    s2 += __shfl_xor(s2, 1);
    const float mu = s1 * 0.0078125f;
    const float rs = rsqrtf(fmaxf(s2 * 0.0078125f - mu * mu, 0.f) + 1e-5f);
    __syncthreads();  // Gg/Gb ready
#pragma unroll
    for (int j = 0; j < 64; j += 4) {
        f32x4 v = *(const f32x4*)(zrow + j);  // re-read, L1/L2 hot
        u16x4 o;
#pragma unroll
        for (int e = 0; e < 4; ++e)
            o[e] = f2b((v[e] - mu) * rs * Gg[h + j + e] + Gb[h + j + e]);
        *(u16x4*)&Zs[r][h + j] = o;
    }
    __syncthreads();

    const int lane = tid & 63, wave = tid >> 6;
    const int wm = (wave >> 1) * 64, wn = (wave & 1) * 64;
    const int lr = lane & 15, quad = lane >> 4, kq = quad * 8;

    // ---- a/b projections: P * sigmoid(G), masked, bf16 channel-major out ----
#pragma unroll 1
    for (int pair = 0; pair < 2; ++pair) {
        const u16* WP = pair ? Wbpb : Wapb;
        const float* BP = pair ? bbp : bap;
        const u16* WG = pair ? Wbgb : Wagb;
        const float* BG = pair ? bbg : bag;
        u16* outp = pair ? b_t : a_t;

#pragma unroll 1
        for (int nh = 0; nh < 2; ++nh) {
            f32x4 accP[4][2], accG[4][2];
#pragma unroll
            for (int i = 0; i < 4; ++i)
#pragma unroll
                for (int j = 0; j < 2; ++j) {
                    accP[i][j] = (f32x4){0.f, 0.f, 0.f, 0.f};
                    accG[i][j] = (f32x4){0.f, 0.f, 0.f, 0.f};
                }
#pragma unroll
            for (int kk = 0; kk < 128; kk += 32) {
                bf16x8 af[4];
#pragma unroll
                for (int mt = 0; mt < 4; ++mt)
                    af[mt] = *(const bf16x8*)&Zs[wm + mt * 16 + lr][kk + kq];
#pragma unroll
                for (int n2 = 0; n2 < 2; ++n2) {
                    const int ncol = wn + (nh * 2 + n2) * 16 + lr;
                    bf16x8 bp8 = *(const bf16x8*)(WP + ncol * 128 + kk + kq);
                    bf16x8 bg8 = *(const bf16x8*)(WG + ncol * 128 + kk + kq);
#pragma unroll
                    for (int mt = 0; mt < 4; ++mt) {
                        accP[mt][n2] = mfma16(af[mt], bp8, accP[mt][n2]);
                        accG[mt][n2] = mfma16(af[mt], bg8, accG[mt][n2]);
                    }
                }
            }
            // C/D layout: col=lane&15 (=ncol), row=quad*4+e -> rows contiguous in [c][row]
#pragma unroll
            for (int n2 = 0; n2 < 2; ++n2) {
                const int ncol = wn + (nh * 2 + n2) * 16 + lr;
                const float bP = BP[ncol];
                const float bG = BG[ncol];
#pragma unroll
                for (int mt = 0; mt < 4; ++mt) {
                    const int rb = wm + mt * 16 + quad * 4;
                    u16x4 o;
#pragma unroll
                    for (int e = 0; e < 4; ++e)
                        o[e] = f2b((accP[mt][n2][e] + bP) * sigmoidf_(accG[mt][n2][e] + bG) * Ms[rb + e]);
                    *(u16x4*)(outp + (size_t)ncol * NROW + row0 + rb) = o;
                }
            }
        }
    }

    // ---- gate = sigmoid(z_norm @ Wg^T + bg), f32, natural layout into d_out ----
    {
        f32x4 acc[4][4];
#pragma unroll
        for (int i = 0; i < 4; ++i)
#pragma unroll
            for (int j = 0; j < 4; ++j) acc[i][j] = (f32x4){0.f, 0.f, 0.f, 0.f};
#pragma unroll
        for (int kk = 0; kk < 128; kk += 32) {
            bf16x8 af[4];
#pragma unroll
            for (int mt = 0; mt < 4; ++mt)
                af[mt] = *(const bf16x8*)&Zs[wm + mt * 16 + lr][kk + kq];
#pragma unroll
            for (int nt = 0; nt < 4; ++nt) {
                bf16x8 bw = *(const bf16x8*)(Wgb + (wn + nt * 16 + lr) * 128 + kk + kq);
#pragma unroll
                for (int mt = 0; mt < 4; ++mt) acc[mt][nt] = mfma16(af[mt], bw, acc[mt][nt]);
            }
        }
#pragma unroll
        for (int nt = 0; nt < 4; ++nt) {
            const int ncol = wn + nt * 16 + lr;
            const float bb = bgv[ncol];
#pragma unroll
            for (int mt = 0; mt < 4; ++mt) {
                const int rb = wm + mt * 16 + quad * 4;
#pragma unroll
                for (int e = 0; e < 4; ++e)
                    gate[(size_t)(row0 + rb + e) * 128 + ncol] = sigmoidf_(acc[mt][nt][e] + bb);
            }
        }
    }
}

// ---------------- Kernel 2: scale[i,j] = rsqrt(max(mask_i . mask_j, 1)) ----------------
__global__ __launch_bounds__(256, 2)
void k2_scale(const float* __restrict__ mask, float* __restrict__ scale)
{
    __shared__ __align__(16) u16 As[128][72];
    __shared__ __align__(16) u16 Bs[128][72];

    const int tid = threadIdx.x;
    const int i0 = (blockIdx.x >> 2) * 128, j0 = (blockIdx.x & 3) * 128;
    const int lane = tid & 63, wave = tid >> 6;
    const int wm = (wave >> 1) * 64, wn = (wave & 1) * 64;
    const int lr = lane & 15, quad = lane >> 4, kq = quad * 8;

    f32x4 acc[4][4];
#pragma unroll
    for (int i = 0; i < 4; ++i)
#pragma unroll
        for (int j = 0; j < 4; ++j) acc[i][j] = (f32x4){0.f, 0.f, 0.f, 0.f};

    for (int kc = 0; kc < LL; kc += 64) {
#pragma unroll
        for (int p = 0; p < 8; ++p) {
            const int q = p * 256 + tid, rr = q >> 4, ko = (q & 15) * 4;
            f32x4 va = *(const f32x4*)(mask + (size_t)(i0 + rr) * LL + kc + ko);
            f32x4 vb = *(const f32x4*)(mask + (size_t)(j0 + rr) * LL + kc + ko);
            u16x4 ca, cb;
#pragma unroll
            for (int e = 0; e < 4; ++e) { ca[e] = f2b(va[e]); cb[e] = f2b(vb[e]); }
            *(u16x4*)&As[rr][ko] = ca;
            *(u16x4*)&Bs[rr][ko] = cb;
        }
        __syncthreads();
#pragma unroll
        for (int kk = 0; kk < 64; kk += 32) {
            bf16x8 af[4], bf[4];
#pragma unroll
            for (int mt = 0; mt < 4; ++mt) af[mt] = *(const bf16x8*)&As[wm + mt * 16 + lr][kk + kq];
#pragma unroll
            for (int nt = 0; nt < 4; ++nt) bf[nt] = *(const bf16x8*)&Bs[wn + nt * 16 + lr][kk + kq];
#pragma unroll
            for (int mt = 0; mt < 4; ++mt)
#pragma unroll
                for (int nt = 0; nt < 4; ++nt) acc[mt][nt] = mfma16(af[mt], bf[nt], acc[mt][nt]);
        }
        __syncthreads();
    }
#pragma unroll
    for (int mt = 0; mt < 4; ++mt)
#pragma unroll
        for (int nt = 0; nt < 4; ++nt) {
            const int gj = j0 + wn + nt * 16 + lr;
#pragma unroll
            for (int e = 0; e < 4; ++e) {
                const int gi = i0 + wm + mt * 16 + quad * 4 + e;
                scale[(size_t)gi * LL + gj] = rsqrtf(fmaxf(acc[mt][nt][e], 1.0f));
            }
        }
}

// ---------------- Kernel 3: triangle einsum, per-channel C = A.B^T ----------------
// grid 2048 = 8 XCDs x (16 channels x 16 tiles); a channel's 16 tiles share one XCD's L2.
__global__ __launch_bounds__(256, 3)
void k3_einsum(const u16* __restrict__ a_t, const u16* __restrict__ b_t,
               const float* __restrict__ scale, u16* __restrict__ x_t)
{
    __shared__ __align__(16) u16 pool[2 * 128 * 72];  // As|Bs, reused as Ss post-K-loop
    u16 (*As)[72] = (u16(*)[72])pool;
    u16 (*Bs)[72] = (u16(*)[72])(pool + 128 * 72);
    u16 (*Ss)[128] = (u16(*)[128])pool;

    const int bid = blockIdx.x;
    const int xcd = bid & 7, slot = bid >> 3;
    const int c = xcd * 16 + (slot >> 4);
    const int tile = slot & 15;
    const int i0 = (tile >> 2) * 128, j0 = (tile & 3) * 128;

    const u16* A = a_t + (size_t)c * NROW;
    const u16* B = b_t + (size_t)c * NROW;

    const int tid = threadIdx.x;
    const int lane = tid & 63, wave = tid >> 6;
    const int wm = (wave >> 1) * 64, wn = (wave & 1) * 64;
    const int lr = lane & 15, quad = lane >> 4, kq = quad * 8;

    f32x4 acc[4][4];
#pragma unroll
    for (int i = 0; i < 4; ++i)
#pragma unroll
        for (int j = 0; j < 4; ++j) acc[i][j] = (f32x4){0.f, 0.f, 0.f, 0.f};

    for (int kc = 0; kc < LL; kc += 64) {
#pragma unroll
        for (int p = 0; p < 4; ++p) {
            const int q = p * 256 + tid, rr = q >> 3, ko = (q & 7) * 8;
            *(u16x8*)&As[rr][ko] = *(const u16x8*)(A + (size_t)(i0 + rr) * LL + kc + ko);
            *(u16x8*)&Bs[rr][ko] = *(const u16x8*)(B + (size_t)(j0 + rr) * LL + kc + ko);
        }
        __syncthreads();
#pragma unroll
        for (int kk = 0; kk < 64; kk += 32) {
            bf16x8 af[4], bf[4];
#pragma unroll
            for (int mt = 0; mt < 4; ++mt) af[mt] = *(const bf16x8*)&As[wm + mt * 16 + lr][kk + kq];
#pragma unroll
            for (int nt = 0; nt < 4; ++nt) bf[nt] = *(const bf16x8*)&Bs[wn + nt * 16 + lr][kk + kq];
#pragma unroll
            for (int mt = 0; mt < 4; ++mt)
#pragma unroll
                for (int nt = 0; nt < 4; ++nt) acc[mt][nt] = mfma16(af[mt], bf[nt], acc[mt][nt]);
        }
        __syncthreads();  // also guards pool reuse below on last iteration
    }
    // epilogue: x = acc * scale[i,j] -> bf16, stash (pool reuse) then coalesced store
#pragma unroll
    for (int mt = 0; mt < 4; ++mt)
#pragma unroll
        for (int nt = 0; nt < 4; ++nt) {
            const int cc = wn + nt * 16 + lr;
#pragma unroll
            for (int e = 0; e < 4; ++e) {
                const int rr = wm + mt * 16 + quad * 4 + e;
                const float s = scale[(size_t)(i0 + rr) * LL + j0 + cc];
                Ss[rr][cc] = f2b(acc[mt][nt][e] * s);
            }
        }
    __syncthreads();
#pragma unroll
    for (int p = 0; p < 8; ++p) {
        const int rr = p * 16 + (tid >> 4);
        const int jo = (tid & 15) * 8;
        *(u16x8*)(x_t + (size_t)c * NROW + (size_t)(i0 + rr) * LL + j0 + jo) = *(const u16x8*)&Ss[rr][jo];
    }
}

// ---------------- Kernel 4: LN(x) @ Wo^T + bo, * gate * mask ----------------
// gate/out both alias d_out f32: each lane reads gate[idx] then writes out[idx]
// at the SAME address (per-lane ordered, no cross-thread hazard).
__global__ __launch_bounds__(256, 3)
void k4_out(const u16* __restrict__ x_t, const float* __restrict__ mask,
            const float* __restrict__ lg, const float* __restrict__ lb,
            const u16* __restrict__ Wob, const float* __restrict__ bo,
            const float* gate, float* out)
{
    __shared__ __align__(16) u16 Zs[128][136];  // x_norm bf16 tile
    __shared__ float Ms[128];

    const int tid = threadIdx.x;
    const int row0 = blockIdx.x * 128;

    if (tid < 128) Ms[tid] = mask[row0 + tid];

    {   // transpose-stage x_t[c][ij] -> Zs[ij][c] via in-register 4x4 transpose
        const int ijo = (tid & 31) * 4;
        const int cb = (tid >> 5) * 4;
#pragma unroll
        for (int p = 0; p < 4; ++p) {
            const int c = p * 32 + cb;
            u16x4 v0 = *(const u16x4*)(x_t + (size_t)(c + 0) * NROW + row0 + ijo);
            u16x4 v1 = *(const u16x4*)(x_t + (size_t)(c + 1) * NROW + row0 + ijo);
            u16x4 v2 = *(const u16x4*)(x_t + (size_t)(c + 2) * NROW + row0 + ijo);
            u16x4 v3 = *(const u16x4*)(x_t + (size_t)(c + 3) * NROW + row0 + ijo);
#pragma unroll
            for (int i = 0; i < 4; ++i) {
                u16x4 w = { v0[i], v1[i], v2[i], v3[i] };
                *(u16x4*)&Zs[ijo + i][c] = w;
            }
        }
    }
    __syncthreads();

    // in-place LN over rows of Zs (bf16 -> f32 stats -> bf16)
    {
        const int r = tid >> 1, h = (tid & 1) * 64;
        float s1 = 0.f, s2 = 0.f;
#pragma unroll
        for (int j = 0; j < 64; j += 8) {
            u16x8 v = *(const u16x8*)&Zs[r][h + j];
#pragma unroll
            for (int e = 0; e < 8; ++e) { float x = b2f(v[e]); s1 += x; s2 += x * x; }
        }
        s1 += __shfl_xor(s1, 1);
        s2 += __shfl_xor(s2, 1);
        const float mu = s1 * 0.0078125f;
        const float rs = rsqrtf(fmaxf(s2 * 0.0078125f - mu * mu, 0.f) + 1e-5f);
#pragma unroll
        for (int j = 0; j < 64; j += 8) {
            const int c = h + j;
            u16x8 v = *(const u16x8*)&Zs[r][c];
            u16x8 o;
#pragma unroll
            for (int e = 0; e < 8; ++e)
                o[e] = f2b((b2f(v[e]) - mu) * rs * lg[c + e] + lb[c + e]);
            *(u16x8*)&Zs[r][c] = o;
        }
    }
    __syncthreads();

    const int lane = tid & 63, wave = tid >> 6;
    const int wm = (wave >> 1) * 64, wn = (wave & 1) * 64;
    const int lr = lane & 15, quad = lane >> 4, kq = quad * 8;

    f32x4 acc[4][4];
#pragma unroll
    for (int i = 0; i < 4; ++i)
#pragma unroll
        for (int j = 0; j < 4; ++j) acc[i][j] = (f32x4){0.f, 0.f, 0.f, 0.f};

#pragma unroll
    for (int kk = 0; kk < 128; kk += 32) {
        bf16x8 af[4];
#pragma unroll
        for (int mt = 0; mt < 4; ++mt)
            af[mt] = *(const bf16x8*)&Zs[wm + mt * 16 + lr][kk + kq];
#pragma unroll
        for (int nt = 0; nt < 4; ++nt) {
            bf16x8 bw = *(const bf16x8*)(Wob + (wn + nt * 16 + lr) * 128 + kk + kq);
#pragma unroll
            for (int mt = 0; mt < 4; ++mt) acc[mt][nt] = mfma16(af[mt], bw, acc[mt][nt]);
        }
    }
#pragma unroll
    for (int nt = 0; nt < 4; ++nt) {
        const int cc = wn + nt * 16 + lr;
        const float bb = bo[cc];
#pragma unroll
        for (int mt = 0; mt < 4; ++mt) {
            const int rb = wm + mt * 16 + quad * 4;
#pragma unroll
            for (int e = 0; e < 4; ++e) {
                const size_t idx = (size_t)(row0 + rb + e) * 128 + cc;
                const float g = gate[idx];           // read own element
                out[idx] = (acc[mt][nt][e] + bb) * g * Ms[rb + e];  // then overwrite it
            }
        }
    }
}

// ---------------- launcher ----------------
// ws: a_t 64MiB + b_t 64MiB + x_t 64MiB + wbf 192KiB + scale 1MiB ~= 193.2 MiB.
// gate lives in d_out (f32), k4 reads-then-writes the same addresses per lane.
extern "C" void kernel_launch(void* const* d_in, const int* in_sizes, int n_in,
                              void* d_out, int out_size, void* d_ws, size_t ws_size,
                              hipStream_t stream)
{
    const float* z        = (const float*)d_in[0];
    const float* mask     = (const float*)d_in[1];
    const float* ln_in_g  = (const float*)d_in[2];
    const float* ln_in_b  = (const float*)d_in[3];
    const float* Wap      = (const float*)d_in[4];
    const float* bap      = (const float*)d_in[5];
    const float* Wbp      = (const float*)d_in[6];
    const float* bbp      = (const float*)d_in[7];
    const float* Wag      = (const float*)d_in[8];
    const float* bag      = (const float*)d_in[9];
    const float* Wbg      = (const float*)d_in[10];
    const float* bbg      = (const float*)d_in[11];
    const float* ln_out_g = (const float*)d_in[12];
    const float* ln_out_b = (const float*)d_in[13];
    const float* Wo       = (const float*)d_in[14];
    const float* bo       = (const float*)d_in[15];
    const float* Wg       = (const float*)d_in[16];
    const float* bg       = (const float*)d_in[17];

    u16* a_t = (u16*)d_ws;
    u16* b_t = a_t + (size_t)128 * NROW;
    u16* x_t = b_t + (size_t)128 * NROW;
    u16* wbf = x_t + (size_t)128 * NROW;         // 6 x 16384 bf16 weights
    float* scale = (float*)(wbf + 6 * 16384);    // byte offset is 16-aligned
    float* gate = (float*)d_out;
    float* out  = (float*)d_out;

    const u16* Wapb = wbf + 0 * 16384;
    const u16* Wagb = wbf + 1 * 16384;
    const u16* Wbpb = wbf + 2 * 16384;
    const u16* Wbgb = wbf + 3 * 16384;
    const u16* Wgb  = wbf + 4 * 16384;
    const u16* Wob  = wbf + 5 * 16384;

    k0_wconv<<<dim3(384), dim3(256), 0, stream>>>(Wap, Wag, Wbp, Wbg, Wg, Wo, wbf);
    k1_ln_proj<<<dim3(2048), dim3(256), 0, stream>>>(z, mask, ln_in_g, ln_in_b,
        Wapb, bap, Wagb, bag, Wbpb, bbp, Wbgb, bbg, Wgb, bg, a_t, b_t, gate);
    k2_scale<<<dim3(16), dim3(256), 0, stream>>>(mask, scale);
    k3_einsum<<<dim3(2048), dim3(256), 0, stream>>>(a_t, b_t, scale, x_t);
    k4_out<<<dim3(2048), dim3(256), 0, stream>>>(x_t, mask, ln_out_g, ln_out_b, Wob, bo, gate, out);
}

// Round 3
// 626.890 us; speedup vs baseline: 1.2801x; 1.2405x over previous
//
#include <hip/hip_runtime.h>
#include <stdint.h>

typedef unsigned short u16;
typedef __bf16 bf16x8 __attribute__((ext_vector_type(8)));
typedef float  f32x4 __attribute__((ext_vector_type(4)));
typedef u16    u16x8 __attribute__((ext_vector_type(8)));
typedef u16    u16x4 __attribute__((ext_vector_type(4)));

constexpr int LL = 512;
constexpr int NROW = LL * LL;   // 262144 flat rows (i*L+k or i*L+j)

__device__ __forceinline__ u16 f2b(float f) {
    __bf16 h = (__bf16)f;                 // RNE
    return __builtin_bit_cast(u16, h);
}
__device__ __forceinline__ float b2f(u16 s) {
    union { unsigned u; float f; } v; v.u = ((unsigned)s) << 16; return v.f;
}
__device__ __forceinline__ float sigmoidf_(float x) { return 1.0f / (1.0f + __expf(-x)); }

__device__ __forceinline__ f32x4 mfma16(bf16x8 a, bf16x8 b, f32x4 c) {
    return __builtin_amdgcn_mfma_f32_16x16x32_bf16(a, b, c, 0, 0, 0);
}

// ---------------- Kernel 0: weights f32 -> bf16 (one-time, tiny) ----------------
__global__ __launch_bounds__(256)
void k0_wconv(const float* __restrict__ Wap, const float* __restrict__ Wag,
              const float* __restrict__ Wbp, const float* __restrict__ Wbg,
              const float* __restrict__ Wg, const float* __restrict__ Wo,
              u16* __restrict__ wbf)
{
    const float* srcs[6] = {Wap, Wag, Wbp, Wbg, Wg, Wo};
    const int m = blockIdx.x >> 6;                       // 64 blocks per 16384-elem matrix
    const int e = ((blockIdx.x & 63) << 8) | threadIdx.x;
    wbf[m * 16384 + e] = f2b(srcs[m][e]);
}

// ---------------- Kernel 1 (fused): scale tiles (blocks 0..15) + LN(z)+projections ----
// LN path: z f32 [NROW][128], two-pass LN (re-read L1/L2-hot), z_norm bf16 tile in LDS.
// Outputs: a_t,b_t bf16 channel-major [c][NROW]; z_norm bf16 into d_out block-region
// ((float*)d_out + row0*128, 32KB per block, read back by k4's same-row block).
// Gate GEMM moved to k4 (was 1/5 of k1's MFMA + 134MB f32 write).
// (256,2): 128 arch + 128 acc = 256-reg budget exactly; (256,3)/(256,4) both spilled (r1/r2).
__global__ __launch_bounds__(256, 2)
void k1_ln_proj(const float* __restrict__ z, const float* __restrict__ mask,
                const float* __restrict__ lg, const float* __restrict__ lb,
                const u16* __restrict__ Wapb, const float* __restrict__ bap,
                const u16* __restrict__ Wagb, const float* __restrict__ bag,
                const u16* __restrict__ Wbpb, const float* __restrict__ bbp,
                const u16* __restrict__ Wbgb, const float* __restrict__ bbg,
                u16* __restrict__ a_t, u16* __restrict__ b_t,
                float* __restrict__ scale, float* zn_out)
{
    __shared__ __align__(16) u16 pool[18432];   // 36,864 B: max(LN path 36,352, scale path 36,864)

    const int tid = threadIdx.x;
    const int lane = tid & 63, wave = tid >> 6;
    const int wm = (wave >> 1) * 64, wn = (wave & 1) * 64;
    const int lr = lane & 15, quad = lane >> 4, kq = quad * 8;

    if (blockIdx.x < 16) {
        // ---- scale[i,j] = rsqrt(max(mask_i . mask_j, 1)) ; depends only on mask ----
        u16 (*As)[72] = (u16(*)[72])pool;
        u16 (*Bs)[72] = (u16(*)[72])(pool + 128 * 72);
        const int sb = blockIdx.x;
        const int i0 = (sb >> 2) * 128, j0 = (sb & 3) * 128;

        f32x4 acc[4][4];
#pragma unroll
        for (int i = 0; i < 4; ++i)
#pragma unroll
            for (int j = 0; j < 4; ++j) acc[i][j] = (f32x4){0.f, 0.f, 0.f, 0.f};

        for (int kc = 0; kc < LL; kc += 64) {
#pragma unroll
            for (int p = 0; p < 8; ++p) {
                const int q = p * 256 + tid, rr = q >> 4, ko = (q & 15) * 4;
                f32x4 va = *(const f32x4*)(mask + (size_t)(i0 + rr) * LL + kc + ko);
                f32x4 vb = *(const f32x4*)(mask + (size_t)(j0 + rr) * LL + kc + ko);
                u16x4 ca, cb;
#pragma unroll
                for (int e = 0; e < 4; ++e) { ca[e] = f2b(va[e]); cb[e] = f2b(vb[e]); }
                *(u16x4*)&As[rr][ko] = ca;
                *(u16x4*)&Bs[rr][ko] = cb;
            }
            __syncthreads();
#pragma unroll
            for (int kk = 0; kk < 64; kk += 32) {
                bf16x8 af[4], bf[4];
#pragma unroll
                for (int mt = 0; mt < 4; ++mt) af[mt] = *(const bf16x8*)&As[wm + mt * 16 + lr][kk + kq];
#pragma unroll
                for (int nt = 0; nt < 4; ++nt) bf[nt] = *(const bf16x8*)&Bs[wn + nt * 16 + lr][kk + kq];
#pragma unroll
                for (int mt = 0; mt < 4; ++mt)
#pragma unroll
                    for (int nt = 0; nt < 4; ++nt) acc[mt][nt] = mfma16(af[mt], bf[nt], acc[mt][nt]);
            }
            __syncthreads();
        }
#pragma unroll
        for (int mt = 0; mt < 4; ++mt)
#pragma unroll
            for (int nt = 0; nt < 4; ++nt) {
                const int gj = j0 + wn + nt * 16 + lr;
#pragma unroll
                for (int e = 0; e < 4; ++e) {
                    const int gi = i0 + wm + mt * 16 + quad * 4 + e;
                    scale[(size_t)gi * LL + gj] = rsqrtf(fmaxf(acc[mt][nt][e], 1.0f));
                }
            }
        return;
    }

    // ---- LN + projections path ----
    u16 (*Zs)[136] = (u16(*)[136])pool;         // 17,408 u16 = 34,816 B
    float* Gg = (float*)(pool + 17408);         // +512 B
    float* Gb = Gg + 128;                       // +512 B
    float* Ms = Gb + 128;                       // +512 B  (total 36,352 B)

    const int row0 = (blockIdx.x - 16) * 128;

    if (tid < 128) { Gg[tid] = lg[tid]; Gb[tid] = lb[tid]; Ms[tid] = mask[row0 + tid]; }

    // LN phase: pair (2r,2r+1) owns row r; halves h=0/64
    const int r = tid >> 1, h = (tid & 1) * 64;
    const float* zrow = z + (size_t)(row0 + r) * 128 + h;
    float s1 = 0.f, s2 = 0.f;
#pragma unroll
    for (int j = 0; j < 64; j += 4) {
        f32x4 v = *(const f32x4*)(zrow + j);
#pragma unroll
        for (int e = 0; e < 4; ++e) { s1 += v[e]; s2 += v[e] * v[e]; }
    }
    s1 += __shfl_xor(s1, 1);
    s2 += __shfl_xor(s2, 1);
    const float mu = s1 * 0.0078125f;
    const float rs = rsqrtf(fmaxf(s2 * 0.0078125f - mu * mu, 0.f) + 1e-5f);
    __syncthreads();  // Gg/Gb ready
#pragma unroll
    for (int j = 0; j < 64; j += 4) {
        f32x4 v = *(const f32x4*)(zrow + j);  // re-read, L1/L2 hot
        u16x4 o;
#pragma unroll
        for (int e = 0; e < 4; ++e)
            o[e] = f2b((v[e] - mu) * rs * Gg[h + j + e] + Gb[h + j + e]);
        *(u16x4*)&Zs[r][h + j] = o;
    }
    __syncthreads();

    // z_norm bf16 -> d_out block-region (k4 re-reads it for the gate GEMM)
    {
        u16* znb = (u16*)(zn_out + (size_t)row0 * 128);
#pragma unroll
        for (int p = 0; p < 8; ++p) {
            const int idx = p * 256 + tid;
            const int rr = idx >> 4, co = (idx & 15) * 8;
            *(u16x8*)(znb + rr * 128 + co) = *(const u16x8*)&Zs[rr][co];
        }
    }

    // a/b projections: P * sigmoid(G), masked, bf16 channel-major out
#pragma unroll 1
    for (int pair = 0; pair < 2; ++pair) {
        const u16* WP = pair ? Wbpb : Wapb;
        const float* BP = pair ? bbp : bap;
        const u16* WG = pair ? Wbgb : Wagb;
        const float* BG = pair ? bbg : bag;
        u16* outp = pair ? b_t : a_t;

        f32x4 accP[4][4], accG[4][4];
#pragma unroll
        for (int i = 0; i < 4; ++i)
#pragma unroll
            for (int j = 0; j < 4; ++j) {
                accP[i][j] = (f32x4){0.f, 0.f, 0.f, 0.f};
                accG[i][j] = (f32x4){0.f, 0.f, 0.f, 0.f};
            }
#pragma unroll
        for (int kk = 0; kk < 128; kk += 32) {
            bf16x8 af[4];
#pragma unroll
            for (int mt = 0; mt < 4; ++mt)
                af[mt] = *(const bf16x8*)&Zs[wm + mt * 16 + lr][kk + kq];
#pragma unroll
            for (int nt = 0; nt < 4; ++nt) {
                const int ncol = wn + nt * 16 + lr;
                bf16x8 bp8 = *(const bf16x8*)(WP + ncol * 128 + kk + kq);
                bf16x8 bg8 = *(const bf16x8*)(WG + ncol * 128 + kk + kq);
#pragma unroll
                for (int mt = 0; mt < 4; ++mt) {
                    accP[mt][nt] = mfma16(af[mt], bp8, accP[mt][nt]);
                    accG[mt][nt] = mfma16(af[mt], bg8, accG[mt][nt]);
                }
            }
        }
        // C/D layout: col=lane&15 (=ncol), row=quad*4+e -> rows contiguous in [c][row]
#pragma unroll
        for (int nt = 0; nt < 4; ++nt) {
            const int ncol = wn + nt * 16 + lr;
            const float bP = BP[ncol];
            const float bG = BG[ncol];
#pragma unroll
            for (int mt = 0; mt < 4; ++mt) {
                const int rb = wm + mt * 16 + quad * 4;
                u16x4 o;
#pragma unroll
                for (int e = 0; e < 4; ++e)
                    o[e] = f2b((accP[mt][nt][e] + bP) * sigmoidf_(accG[mt][nt][e] + bG) * Ms[rb + e]);
                *(u16x4*)(outp + (size_t)ncol * NROW + row0 + rb) = o;
            }
        }
    }
}

// ---------------- Kernel 3: triangle einsum, per-channel C = A.B^T ----------------
// grid 2048 = 8 XCDs x (16 channels x 16 tiles); a channel's 16 tiles share one XCD's L2.
__global__ __launch_bounds__(256, 2)
void k3_einsum(const u16* __restrict__ a_t, const u16* __restrict__ b_t,
               const float* __restrict__ scale, u16* __restrict__ x_t)
{
    __shared__ __align__(16) u16 pool[2 * 128 * 72];  // As|Bs, reused as Ss post-K-loop
    u16 (*As)[72] = (u16(*)[72])pool;
    u16 (*Bs)[72] = (u16(*)[72])(pool + 128 * 72);
    u16 (*Ss)[128] = (u16(*)[128])pool;

    const int bid = blockIdx.x;
    const int xcd = bid & 7, slot = bid >> 3;
    const int c = xcd * 16 + (slot >> 4);
    const int tile = slot & 15;
    const int i0 = (tile >> 2) * 128, j0 = (tile & 3) * 128;

    const u16* A = a_t + (size_t)c * NROW;
    const u16* B = b_t + (size_t)c * NROW;

    const int tid = threadIdx.x;
    const int lane = tid & 63, wave = tid >> 6;
    const int wm = (wave >> 1) * 64, wn = (wave & 1) * 64;
    const int lr = lane & 15, quad = lane >> 4, kq = quad * 8;

    f32x4 acc[4][4];
#pragma unroll
    for (int i = 0; i < 4; ++i)
#pragma unroll
        for (int j = 0; j < 4; ++j) acc[i][j] = (f32x4){0.f, 0.f, 0.f, 0.f};

    for (int kc = 0; kc < LL; kc += 64) {
#pragma unroll
        for (int p = 0; p < 4; ++p) {
            const int q = p * 256 + tid, rr = q >> 3, ko = (q & 7) * 8;
            *(u16x8*)&As[rr][ko] = *(const u16x8*)(A + (size_t)(i0 + rr) * LL + kc + ko);
            *(u16x8*)&Bs[rr][ko] = *(const u16x8*)(B + (size_t)(j0 + rr) * LL + kc + ko);
        }
        __syncthreads();
#pragma unroll
        for (int kk = 0; kk < 64; kk += 32) {
            bf16x8 af[4], bf[4];
#pragma unroll
            for (int mt = 0; mt < 4; ++mt) af[mt] = *(const bf16x8*)&As[wm + mt * 16 + lr][kk + kq];
#pragma unroll
            for (int nt = 0; nt < 4; ++nt) bf[nt] = *(const bf16x8*)&Bs[wn + nt * 16 + lr][kk + kq];
#pragma unroll
            for (int mt = 0; mt < 4; ++mt)
#pragma unroll
                for (int nt = 0; nt < 4; ++nt) acc[mt][nt] = mfma16(af[mt], bf[nt], acc[mt][nt]);
        }
        __syncthreads();  // also guards pool reuse below on last iteration
    }
    // epilogue: x = acc * scale[i,j] -> bf16, stash (pool reuse) then coalesced store
#pragma unroll
    for (int mt = 0; mt < 4; ++mt)
#pragma unroll
        for (int nt = 0; nt < 4; ++nt) {
            const int cc = wn + nt * 16 + lr;
#pragma unroll
            for (int e = 0; e < 4; ++e) {
                const int rr = wm + mt * 16 + quad * 4 + e;
                const float s = scale[(size_t)(i0 + rr) * LL + j0 + cc];
                Ss[rr][cc] = f2b(acc[mt][nt][e] * s);
            }
        }
    __syncthreads();
#pragma unroll
    for (int p = 0; p < 8; ++p) {
        const int rr = p * 16 + (tid >> 4);
        const int jo = (tid & 15) * 8;
        *(u16x8*)(x_t + (size_t)c * NROW + (size_t)(i0 + rr) * LL + j0 + jo) = *(const u16x8*)&Ss[rr][jo];
    }
}

// ---------------- Kernel 4: LN(x) @ Wo^T + bo, * sigmoid(z_norm @ Wg^T + bg) * mask ----
// z_norm bf16 staged from out's own block-region (written by k1) BEFORE any out write.
// nh-split keeps live accumulators at 64 (peak ~154 unified regs, safe at (256,2)).
__global__ __launch_bounds__(256, 2)
void k4_out(const u16* __restrict__ x_t, const float* __restrict__ mask,
            const float* __restrict__ lg, const float* __restrict__ lb,
            const u16* __restrict__ Wob, const float* __restrict__ bo,
            const u16* __restrict__ Wgb, const float* __restrict__ bgv,
            float* out)
{
    __shared__ __align__(16) u16 Zs[128][136];  // x_norm bf16 tile
    __shared__ __align__(16) u16 Zn[128][136];  // z_norm bf16 tile
    __shared__ float Ms[128];

    const int tid = threadIdx.x;
    const int row0 = blockIdx.x * 128;

    if (tid < 128) Ms[tid] = mask[row0 + tid];

    {   // stage z_norm from out's block-region (must complete before out writes; it does:
        // all reads here, all writes in the final epilogue after __syncthreads)
        const u16* znb = (const u16*)(out + (size_t)row0 * 128);
#pragma unroll
        for (int p = 0; p < 8; ++p) {
            const int idx = p * 256 + tid;
            const int rr = idx >> 4, co = (idx & 15) * 8;
            *(u16x8*)&Zn[rr][co] = *(const u16x8*)(znb + rr * 128 + co);
        }
    }

    {   // transpose-stage x_t[c][ij] -> Zs[ij][c] via in-register 4x4 transpose
        const int ijo = (tid & 31) * 4;
        const int cb = (tid >> 5) * 4;
#pragma unroll
        for (int p = 0; p < 4; ++p) {
            const int c = p * 32 + cb;
            u16x4 v0 = *(const u16x4*)(x_t + (size_t)(c + 0) * NROW + row0 + ijo);
            u16x4 v1 = *(const u16x4*)(x_t + (size_t)(c + 1) * NROW + row0 + ijo);
            u16x4 v2 = *(const u16x4*)(x_t + (size_t)(c + 2) * NROW + row0 + ijo);
            u16x4 v3 = *(const u16x4*)(x_t + (size_t)(c + 3) * NROW + row0 + ijo);
#pragma unroll
            for (int i = 0; i < 4; ++i) {
                u16x4 w = { v0[i], v1[i], v2[i], v3[i] };
                *(u16x4*)&Zs[ijo + i][c] = w;
            }
        }
    }
    __syncthreads();

    // in-place LN over rows of Zs (bf16 -> f32 stats -> bf16)
    {
        const int r = tid >> 1, h = (tid & 1) * 64;
        float s1 = 0.f, s2 = 0.f;
#pragma unroll
        for (int j = 0; j < 64; j += 8) {
            u16x8 v = *(const u16x8*)&Zs[r][h + j];
#pragma unroll
            for (int e = 0; e < 8; ++e) { float x = b2f(v[e]); s1 += x; s2 += x * x; }
        }
        s1 += __shfl_xor(s1, 1);
        s2 += __shfl_xor(s2, 1);
        const float mu = s1 * 0.0078125f;
        const float rs = rsqrtf(fmaxf(s2 * 0.0078125f - mu * mu, 0.f) + 1e-5f);
#pragma unroll
        for (int j = 0; j < 64; j += 8) {
            const int c = h + j;
            u16x8 v = *(const u16x8*)&Zs[r][c];
            u16x8 o;
#pragma unroll
            for (int e = 0; e < 8; ++e)
                o[e] = f2b((b2f(v[e]) - mu) * rs * lg[c + e] + lb[c + e]);
            *(u16x8*)&Zs[r][c] = o;
        }
    }
    __syncthreads();

    const int lane = tid & 63, wave = tid >> 6;
    const int wm = (wave >> 1) * 64, wn = (wave & 1) * 64;
    const int lr = lane & 15, quad = lane >> 4, kq = quad * 8;

#pragma unroll 1
    for (int nh = 0; nh < 2; ++nh) {
        f32x4 accO[4][2], accG[4][2];
#pragma unroll
        for (int i = 0; i < 4; ++i)
#pragma unroll
            for (int j = 0; j < 2; ++j) {
                accO[i][j] = (f32x4){0.f, 0.f, 0.f, 0.f};
                accG[i][j] = (f32x4){0.f, 0.f, 0.f, 0.f};
            }
#pragma unroll
        for (int kk = 0; kk < 128; kk += 32) {
            bf16x8 ax[4], az[4];
#pragma unroll
            for (int mt = 0; mt < 4; ++mt) {
                ax[mt] = *(const bf16x8*)&Zs[wm + mt * 16 + lr][kk + kq];
                az[mt] = *(const bf16x8*)&Zn[wm + mt * 16 + lr][kk + kq];
            }
#pragma unroll
            for (int n2 = 0; n2 < 2; ++n2) {
                const int ncol = wn + (nh * 2 + n2) * 16 + lr;
                bf16x8 bo8 = *(const bf16x8*)(Wob + ncol * 128 + kk + kq);
                bf16x8 bg8 = *(const bf16x8*)(Wgb + ncol * 128 + kk + kq);
#pragma unroll
                for (int mt = 0; mt < 4; ++mt) {
                    accO[mt][n2] = mfma16(ax[mt], bo8, accO[mt][n2]);
                    accG[mt][n2] = mfma16(az[mt], bg8, accG[mt][n2]);
                }
            }
        }
#pragma unroll
        for (int n2 = 0; n2 < 2; ++n2) {
            const int cc = wn + (nh * 2 + n2) * 16 + lr;
            const float bb = bo[cc];
            const float bg = bgv[cc];
#pragma unroll
            for (int mt = 0; mt < 4; ++mt) {
                const int rb = wm + mt * 16 + quad * 4;
#pragma unroll
                for (int e = 0; e < 4; ++e) {
                    const size_t idx = (size_t)(row0 + rb + e) * 128 + cc;
                    out[idx] = (accO[mt][n2][e] + bb) * sigmoidf_(accG[mt][n2][e] + bg) * Ms[rb + e];
                }
            }
        }
    }
}

// ---------------- launcher ----------------
// ws: a_t 64MiB + b_t 64MiB + x_t 64MiB + wbf 192KiB + scale 1MiB ~= 193.2 MiB.
// z_norm bf16 lives in d_out (each block's own 32KB of its 64KB f32 region); k4
// stages it to LDS before overwriting with the final output.
extern "C" void kernel_launch(void* const* d_in, const int* in_sizes, int n_in,
                              void* d_out, int out_size, void* d_ws, size_t ws_size,
                              hipStream_t stream)
{
    const float* z        = (const float*)d_in[0];
    const float* mask     = (const float*)d_in[1];
    const float* ln_in_g  = (const float*)d_in[2];
    const float* ln_in_b  = (const float*)d_in[3];
    const float* Wap      = (const float*)d_in[4];
    const float* bap      = (const float*)d_in[5];
    const float* Wbp      = (const float*)d_in[6];
    const float* bbp      = (const float*)d_in[7];
    const float* Wag      = (const float*)d_in[8];
    const float* bag      = (const float*)d_in[9];
    const float* Wbg      = (const float*)d_in[10];
    const float* bbg      = (const float*)d_in[11];
    const float* ln_out_g = (const float*)d_in[12];
    const float* ln_out_b = (const float*)d_in[13];
    const float* Wo       = (const float*)d_in[14];
    const float* bo       = (const float*)d_in[15];
    const float* Wg       = (const float*)d_in[16];
    const float* bg       = (const float*)d_in[17];

    u16* a_t = (u16*)d_ws;
    u16* b_t = a_t + (size_t)128 * NROW;
    u16* x_t = b_t + (size_t)128 * NROW;
    u16* wbf = x_t + (size_t)128 * NROW;         // 6 x 16384 bf16 weights
    float* scale = (float*)(wbf + 6 * 16384);    // byte offset is 16-aligned
    float* outf  = (float*)d_out;

    const u16* Wapb = wbf + 0 * 16384;
    const u16* Wagb = wbf + 1 * 16384;
    const u16* Wbpb = wbf + 2 * 16384;
    const u16* Wbgb = wbf + 3 * 16384;
    const u16* Wgb  = wbf + 4 * 16384;
    const u16* Wob  = wbf + 5 * 16384;

    k0_wconv<<<dim3(384), dim3(256), 0, stream>>>(Wap, Wag, Wbp, Wbg, Wg, Wo, wbf);
    k1_ln_proj<<<dim3(2064), dim3(256), 0, stream>>>(z, mask, ln_in_g, ln_in_b,
        Wapb, bap, Wagb, bag, Wbpb, bbp, Wbgb, bbg, a_t, b_t, scale, outf);
    k3_einsum<<<dim3(2048), dim3(256), 0, stream>>>(a_t, b_t, scale, x_t);
    k4_out<<<dim3(2048), dim3(256), 0, stream>>>(x_t, mask, ln_out_g, ln_out_b,
        Wob, bo, Wgb, bg, outf);
}

// Round 5
// 614.815 us; speedup vs baseline: 1.3053x; 1.0196x over previous
//
#include <hip/hip_runtime.h>
#include <stdint.h>

typedef unsigned short u16;
typedef __bf16 bf16x8 __attribute__((ext_vector_type(8)));
typedef float  f32x4 __attribute__((ext_vector_type(4)));
typedef u16    u16x8 __attribute__((ext_vector_type(8)));
typedef u16    u16x4 __attribute__((ext_vector_type(4)));

constexpr int LL = 512;
constexpr int NROW = LL * LL;   // 262144 flat rows (i*L+k or i*L+j)

__device__ __forceinline__ u16 f2b(float f) {
    __bf16 h = (__bf16)f;                 // RNE
    return __builtin_bit_cast(u16, h);
}
__device__ __forceinline__ float b2f(u16 s) {
    union { unsigned u; float f; } v; v.u = ((unsigned)s) << 16; return v.f;
}
__device__ __forceinline__ float sigmoidf_(float x) { return 1.0f / (1.0f + __expf(-x)); }

__device__ __forceinline__ f32x4 mfma16(bf16x8 a, bf16x8 b, f32x4 c) {
    return __builtin_amdgcn_mfma_f32_16x16x32_bf16(a, b, c, 0, 0, 0);
}

// ---------------- Kernel 0: weights f32 -> bf16 (one-time, tiny) ----------------
__global__ __launch_bounds__(256)
void k0_wconv(const float* __restrict__ Wap, const float* __restrict__ Wag,
              const float* __restrict__ Wbp, const float* __restrict__ Wbg,
              const float* __restrict__ Wg, const float* __restrict__ Wo,
              u16* __restrict__ wbf)
{
    const float* srcs[6] = {Wap, Wag, Wbp, Wbg, Wg, Wo};
    const int m = blockIdx.x >> 6;                       // 64 blocks per 16384-elem matrix
    const int e = ((blockIdx.x & 63) << 8) | threadIdx.x;
    wbf[m * 16384 + e] = f2b(srcs[m][e]);
}

// ---------------- Kernel 1 (fused): scale tiles (blocks 0..15) + LN(z)+projections ----
// LN: single global pass; z tile held in registers (16 x f32x4/thread) between the
// stats pass and the normalize pass (r3's two-pass re-read missed L2 AND L3: 252MB fetch).
// z_norm block region in d_out: u16 data based at (u16*)(zn_out + row0*128), i.e. byte
// offset row0*512 — MUST match k4's read base (r4 bug: used u16-offset (row0+r)*128,
// half the address -> k4 read garbage gate).
// (256,2): 128 arch + 128 acc = 256-reg budget exactly; (256,3)/(256,4) both spilled (r1/r2).
__global__ __launch_bounds__(256, 2)
void k1_ln_proj(const float* __restrict__ z, const float* __restrict__ mask,
                const float* __restrict__ lg, const float* __restrict__ lb,
                const u16* __restrict__ Wapb, const float* __restrict__ bap,
                const u16* __restrict__ Wagb, const float* __restrict__ bag,
                const u16* __restrict__ Wbpb, const float* __restrict__ bbp,
                const u16* __restrict__ Wbgb, const float* __restrict__ bbg,
                u16* __restrict__ a_t, u16* __restrict__ b_t,
                float* __restrict__ scale, float* zn_out)
{
    __shared__ __align__(16) u16 pool[18432];   // 36,864 B: max(LN path 36,352, scale path 36,864)

    const int tid = threadIdx.x;
    const int lane = tid & 63, wave = tid >> 6;
    const int wm = (wave >> 1) * 64, wn = (wave & 1) * 64;
    const int lr = lane & 15, quad = lane >> 4, kq = quad * 8;

    if (blockIdx.x < 16) {
        // ---- scale[i,j] = rsqrt(max(mask_i . mask_j, 1)) ; depends only on mask ----
        u16 (*As)[72] = (u16(*)[72])pool;
        u16 (*Bs)[72] = (u16(*)[72])(pool + 128 * 72);
        const int sb = blockIdx.x;
        const int i0 = (sb >> 2) * 128, j0 = (sb & 3) * 128;

        f32x4 acc[4][4];
#pragma unroll
        for (int i = 0; i < 4; ++i)
#pragma unroll
            for (int j = 0; j < 4; ++j) acc[i][j] = (f32x4){0.f, 0.f, 0.f, 0.f};

        for (int kc = 0; kc < LL; kc += 64) {
#pragma unroll
            for (int p = 0; p < 8; ++p) {
                const int q = p * 256 + tid, rr = q >> 4, ko = (q & 15) * 4;
                f32x4 va = *(const f32x4*)(mask + (size_t)(i0 + rr) * LL + kc + ko);
                f32x4 vb = *(const f32x4*)(mask + (size_t)(j0 + rr) * LL + kc + ko);
                u16x4 ca, cb;
#pragma unroll
                for (int e = 0; e < 4; ++e) { ca[e] = f2b(va[e]); cb[e] = f2b(vb[e]); }
                *(u16x4*)&As[rr][ko] = ca;
                *(u16x4*)&Bs[rr][ko] = cb;
            }
            __syncthreads();
#pragma unroll
            for (int kk = 0; kk < 64; kk += 32) {
                bf16x8 af[4], bf[4];
#pragma unroll
                for (int mt = 0; mt < 4; ++mt) af[mt] = *(const bf16x8*)&As[wm + mt * 16 + lr][kk + kq];
#pragma unroll
                for (int nt = 0; nt < 4; ++nt) bf[nt] = *(const bf16x8*)&Bs[wn + nt * 16 + lr][kk + kq];
#pragma unroll
                for (int mt = 0; mt < 4; ++mt)
#pragma unroll
                    for (int nt = 0; nt < 4; ++nt) acc[mt][nt] = mfma16(af[mt], bf[nt], acc[mt][nt]);
            }
            __syncthreads();
        }
#pragma unroll
        for (int mt = 0; mt < 4; ++mt)
#pragma unroll
            for (int nt = 0; nt < 4; ++nt) {
                const int gj = j0 + wn + nt * 16 + lr;
#pragma unroll
                for (int e = 0; e < 4; ++e) {
                    const int gi = i0 + wm + mt * 16 + quad * 4 + e;
                    scale[(size_t)gi * LL + gj] = rsqrtf(fmaxf(acc[mt][nt][e], 1.0f));
                }
            }
        return;
    }

    // ---- LN + projections path ----
    u16 (*Zs)[136] = (u16(*)[136])pool;         // 17,408 u16 = 34,816 B
    float* Gg = (float*)(pool + 17408);         // +512 B
    float* Gb = Gg + 128;                       // +512 B
    float* Ms = Gb + 128;                       // +512 B  (total 36,352 B)

    const int row0 = (blockIdx.x - 16) * 128;

    if (tid < 128) { Gg[tid] = lg[tid]; Gb[tid] = lb[tid]; Ms[tid] = mask[row0 + tid]; }

    // LN phase: pair (2r,2r+1) owns row r; halves h=0/64. Single global pass:
    // z half-row lives in 16 f32x4 registers (phase-local; acc regs not yet live).
    {
        const int r = tid >> 1, h = (tid & 1) * 64;
        const float* zrow = z + (size_t)(row0 + r) * 128 + h;
        f32x4 zv[16];
        float s1 = 0.f, s2 = 0.f;
#pragma unroll
        for (int j = 0; j < 16; ++j) {
            zv[j] = *(const f32x4*)(zrow + j * 4);
#pragma unroll
            for (int e = 0; e < 4; ++e) { s1 += zv[j][e]; s2 += zv[j][e] * zv[j][e]; }
        }
        s1 += __shfl_xor(s1, 1);
        s2 += __shfl_xor(s2, 1);
        const float mu = s1 * 0.0078125f;
        const float rs = rsqrtf(fmaxf(s2 * 0.0078125f - mu * mu, 0.f) + 1e-5f);
        __syncthreads();  // Gg/Gb ready
        // block-region base: u16 view of (zn_out + row0*128), then row r, half h
        u16* znb = (u16*)(zn_out + (size_t)row0 * 128) + r * 128 + h;
#pragma unroll
        for (int j = 0; j < 16; ++j) {
            u16x4 o;
#pragma unroll
            for (int e = 0; e < 4; ++e)
                o[e] = f2b((zv[j][e] - mu) * rs * Gg[h + j * 4 + e] + Gb[h + j * 4 + e]);
            *(u16x4*)&Zs[r][h + j * 4] = o;
            *(u16x4*)(znb + j * 4) = o;   // z_norm bf16 -> d_out block-region (k4 gate GEMM)
        }
    }
    __syncthreads();

    // a/b projections: P * sigmoid(G), masked, bf16 channel-major out
#pragma unroll 1
    for (int pair = 0; pair < 2; ++pair) {
        const u16* WP = pair ? Wbpb : Wapb;
        const float* BP = pair ? bbp : bap;
        const u16* WG = pair ? Wbgb : Wagb;
        const float* BG = pair ? bbg : bag;
        u16* outp = pair ? b_t : a_t;

        f32x4 accP[4][4], accG[4][4];
#pragma unroll
        for (int i = 0; i < 4; ++i)
#pragma unroll
            for (int j = 0; j < 4; ++j) {
                accP[i][j] = (f32x4){0.f, 0.f, 0.f, 0.f};
                accG[i][j] = (f32x4){0.f, 0.f, 0.f, 0.f};
            }
#pragma unroll
        for (int kk = 0; kk < 128; kk += 32) {
            bf16x8 af[4];
#pragma unroll
            for (int mt = 0; mt < 4; ++mt)
                af[mt] = *(const bf16x8*)&Zs[wm + mt * 16 + lr][kk + kq];
#pragma unroll
            for (int nt = 0; nt < 4; ++nt) {
                const int ncol = wn + nt * 16 + lr;
                bf16x8 bp8 = *(const bf16x8*)(WP + ncol * 128 + kk + kq);
                bf16x8 bg8 = *(const bf16x8*)(WG + ncol * 128 + kk + kq);
#pragma unroll
                for (int mt = 0; mt < 4; ++mt) {
                    accP[mt][nt] = mfma16(af[mt], bp8, accP[mt][nt]);
                    accG[mt][nt] = mfma16(af[mt], bg8, accG[mt][nt]);
                }
            }
        }
        // C/D layout: col=lane&15 (=ncol), row=quad*4+e -> rows contiguous in [c][row]
#pragma unroll
        for (int nt = 0; nt < 4; ++nt) {
            const int ncol = wn + nt * 16 + lr;
            const float bP = BP[ncol];
            const float bG = BG[ncol];
#pragma unroll
            for (int mt = 0; mt < 4; ++mt) {
                const int rb = wm + mt * 16 + quad * 4;
                u16x4 o;
#pragma unroll
                for (int e = 0; e < 4; ++e)
                    o[e] = f2b((accP[mt][nt][e] + bP) * sigmoidf_(accG[mt][nt][e] + bG) * Ms[rb + e]);
                *(u16x4*)(outp + (size_t)ncol * NROW + row0 + rb) = o;
            }
        }
    }
}

// ---------------- Kernel 3: triangle einsum, per-channel C = A.B^T ----------------
// grid 2048 = 8 XCDs x (16 channels x 16 tiles); a channel's 16 tiles share one XCD's L2.
// BK=128: 4 staging chunks instead of 8 -> half the barriers/vmcnt drains.
// LDS 2 x 128x136 u16 = 69.6 KB -> still 2 blocks/CU (139 < 160 KB).
__global__ __launch_bounds__(256, 2)
void k3_einsum(const u16* __restrict__ a_t, const u16* __restrict__ b_t,
               const float* __restrict__ scale, u16* __restrict__ x_t)
{
    __shared__ __align__(16) u16 pool[2 * 128 * 136];  // As|Bs, reused as Ss post-K-loop
    u16 (*As)[136] = (u16(*)[136])pool;
    u16 (*Bs)[136] = (u16(*)[136])(pool + 128 * 136);
    u16 (*Ss)[128] = (u16(*)[128])pool;

    const int bid = blockIdx.x;
    const int xcd = bid & 7, slot = bid >> 3;
    const int c = xcd * 16 + (slot >> 4);
    const int tile = slot & 15;
    const int i0 = (tile >> 2) * 128, j0 = (tile & 3) * 128;

    const u16* A = a_t + (size_t)c * NROW;
    const u16* B = b_t + (size_t)c * NROW;

    const int tid = threadIdx.x;
    const int lane = tid & 63, wave = tid >> 6;
    const int wm = (wave >> 1) * 64, wn = (wave & 1) * 64;
    const int lr = lane & 15, quad = lane >> 4, kq = quad * 8;

    f32x4 acc[4][4];
#pragma unroll
    for (int i = 0; i < 4; ++i)
#pragma unroll
        for (int j = 0; j < 4; ++j) acc[i][j] = (f32x4){0.f, 0.f, 0.f, 0.f};

    for (int kc = 0; kc < LL; kc += 128) {
#pragma unroll
        for (int p = 0; p < 8; ++p) {
            const int q = p * 256 + tid, rr = q >> 4, ko = (q & 15) * 8;
            *(u16x8*)&As[rr][ko] = *(const u16x8*)(A + (size_t)(i0 + rr) * LL + kc + ko);
            *(u16x8*)&Bs[rr][ko] = *(const u16x8*)(B + (size_t)(j0 + rr) * LL + kc + ko);
        }
        __syncthreads();
#pragma unroll
        for (int kk = 0; kk < 128; kk += 32) {
            bf16x8 af[4], bf[4];
#pragma unroll
            for (int mt = 0; mt < 4; ++mt) af[mt] = *(const bf16x8*)&As[wm + mt * 16 + lr][kk + kq];
#pragma unroll
            for (int nt = 0; nt < 4; ++nt) bf[nt] = *(const bf16x8*)&Bs[wn + nt * 16 + lr][kk + kq];
#pragma unroll
            for (int mt = 0; mt < 4; ++mt)
#pragma unroll
                for (int nt = 0; nt < 4; ++nt) acc[mt][nt] = mfma16(af[mt], bf[nt], acc[mt][nt]);
        }
        __syncthreads();  // also guards pool reuse below on last iteration
    }
    // epilogue: x = acc * scale[i,j] -> bf16, stash (pool reuse) then coalesced store
#pragma unroll
    for (int mt = 0; mt < 4; ++mt)
#pragma unroll
        for (int nt = 0; nt < 4; ++nt) {
            const int cc = wn + nt * 16 + lr;
#pragma unroll
            for (int e = 0; e < 4; ++e) {
                const int rr = wm + mt * 16 + quad * 4 + e;
                const float s = scale[(size_t)(i0 + rr) * LL + j0 + cc];
                Ss[rr][cc] = f2b(acc[mt][nt][e] * s);
            }
        }
    __syncthreads();
#pragma unroll
    for (int p = 0; p < 8; ++p) {
        const int rr = p * 16 + (tid >> 4);
        const int jo = (tid & 15) * 8;
        *(u16x8*)(x_t + (size_t)c * NROW + (size_t)(i0 + rr) * LL + j0 + jo) = *(const u16x8*)&Ss[rr][jo];
    }
}

// ---------------- Kernel 4: LN(x) @ Wo^T + bo, * sigmoid(z_norm @ Wg^T + bg) * mask ----
// z_norm bf16 staged from out's own block-region (written by k1) BEFORE any out write.
// nh-split keeps live accumulators at 64 (peak ~154 unified regs, safe at (256,2)).
__global__ __launch_bounds__(256, 2)
void k4_out(const u16* __restrict__ x_t, const float* __restrict__ mask,
            const float* __restrict__ lg, const float* __restrict__ lb,
            const u16* __restrict__ Wob, const float* __restrict__ bo,
            const u16* __restrict__ Wgb, const float* __restrict__ bgv,
            float* out)
{
    __shared__ __align__(16) u16 Zs[128][136];  // x_norm bf16 tile
    __shared__ __align__(16) u16 Zn[128][136];  // z_norm bf16 tile
    __shared__ float Ms[128];

    const int tid = threadIdx.x;
    const int row0 = blockIdx.x * 128;

    if (tid < 128) Ms[tid] = mask[row0 + tid];

    {   // stage z_norm from out's block-region (must complete before out writes; it does:
        // all reads here, all writes in the final epilogue after __syncthreads)
        const u16* znb = (const u16*)(out + (size_t)row0 * 128);
#pragma unroll
        for (int p = 0; p < 8; ++p) {
            const int idx = p * 256 + tid;
            const int rr = idx >> 4, co = (idx & 15) * 8;
            *(u16x8*)&Zn[rr][co] = *(const u16x8*)(znb + rr * 128 + co);
        }
    }

    {   // transpose-stage x_t[c][ij] -> Zs[ij][c] via in-register 4x4 transpose
        const int ijo = (tid & 31) * 4;
        const int cb = (tid >> 5) * 4;
#pragma unroll
        for (int p = 0; p < 4; ++p) {
            const int c = p * 32 + cb;
            u16x4 v0 = *(const u16x4*)(x_t + (size_t)(c + 0) * NROW + row0 + ijo);
            u16x4 v1 = *(const u16x4*)(x_t + (size_t)(c + 1) * NROW + row0 + ijo);
            u16x4 v2 = *(const u16x4*)(x_t + (size_t)(c + 2) * NROW + row0 + ijo);
            u16x4 v3 = *(const u16x4*)(x_t + (size_t)(c + 3) * NROW + row0 + ijo);
#pragma unroll
            for (int i = 0; i < 4; ++i) {
                u16x4 w = { v0[i], v1[i], v2[i], v3[i] };
                *(u16x4*)&Zs[ijo + i][c] = w;
            }
        }
    }
    __syncthreads();

    // in-place LN over rows of Zs (bf16 -> f32 stats -> bf16)
    {
        const int r = tid >> 1, h = (tid & 1) * 64;
        float s1 = 0.f, s2 = 0.f;
#pragma unroll
        for (int j = 0; j < 64; j += 8) {
            u16x8 v = *(const u16x8*)&Zs[r][h + j];
#pragma unroll
            for (int e = 0; e < 8; ++e) { float x = b2f(v[e]); s1 += x; s2 += x * x; }
        }
        s1 += __shfl_xor(s1, 1);
        s2 += __shfl_xor(s2, 1);
        const float mu = s1 * 0.0078125f;
        const float rs = rsqrtf(fmaxf(s2 * 0.0078125f - mu * mu, 0.f) + 1e-5f);
#pragma unroll
        for (int j = 0; j < 64; j += 8) {
            const int c = h + j;
            u16x8 v = *(const u16x8*)&Zs[r][c];
            u16x8 o;
#pragma unroll
            for (int e = 0; e < 8; ++e)
                o[e] = f2b((b2f(v[e]) - mu) * rs * lg[c + e] + lb[c + e]);
            *(u16x8*)&Zs[r][c] = o;
        }
    }
    __syncthreads();

    const int lane = tid & 63, wave = tid >> 6;
    const int wm = (wave >> 1) * 64, wn = (wave & 1) * 64;
    const int lr = lane & 15, quad = lane >> 4, kq = quad * 8;

#pragma unroll 1
    for (int nh = 0; nh < 2; ++nh) {
        f32x4 accO[4][2], accG[4][2];
#pragma unroll
        for (int i = 0; i < 4; ++i)
#pragma unroll
            for (int j = 0; j < 2; ++j) {
                accO[i][j] = (f32x4){0.f, 0.f, 0.f, 0.f};
                accG[i][j] = (f32x4){0.f, 0.f, 0.f, 0.f};
            }
#pragma unroll
        for (int kk = 0; kk < 128; kk += 32) {
            bf16x8 ax[4], az[4];
#pragma unroll
            for (int mt = 0; mt < 4; ++mt) {
                ax[mt] = *(const bf16x8*)&Zs[wm + mt * 16 + lr][kk + kq];
                az[mt] = *(const bf16x8*)&Zn[wm + mt * 16 + lr][kk + kq];
            }
#pragma unroll
            for (int n2 = 0; n2 < 2; ++n2) {
                const int ncol = wn + (nh * 2 + n2) * 16 + lr;
                bf16x8 bo8 = *(const bf16x8*)(Wob + ncol * 128 + kk + kq);
                bf16x8 bg8 = *(const bf16x8*)(Wgb + ncol * 128 + kk + kq);
#pragma unroll
                for (int mt = 0; mt < 4; ++mt) {
                    accO[mt][n2] = mfma16(ax[mt], bo8, accO[mt][n2]);
                    accG[mt][n2] = mfma16(az[mt], bg8, accG[mt][n2]);
                }
            }
        }
#pragma unroll
        for (int n2 = 0; n2 < 2; ++n2) {
            const int cc = wn + (nh * 2 + n2) * 16 + lr;
            const float bb = bo[cc];
            const float bg = bgv[cc];
#pragma unroll
            for (int mt = 0; mt < 4; ++mt) {
                const int rb = wm + mt * 16 + quad * 4;
#pragma unroll
                for (int e = 0; e < 4; ++e) {
                    const size_t idx = (size_t)(row0 + rb + e) * 128 + cc;
                    out[idx] = (accO[mt][n2][e] + bb) * sigmoidf_(accG[mt][n2][e] + bg) * Ms[rb + e];
                }
            }
        }
    }
}

// ---------------- launcher ----------------
// ws: a_t 64MiB + b_t 64MiB + x_t 64MiB + wbf 192KiB + scale 1MiB ~= 193.2 MiB.
// z_norm bf16 lives in d_out (each block's own 32KB of its 64KB f32 region); k4
// stages it to LDS before overwriting with the final output.
extern "C" void kernel_launch(void* const* d_in, const int* in_sizes, int n_in,
                              void* d_out, int out_size, void* d_ws, size_t ws_size,
                              hipStream_t stream)
{
    const float* z        = (const float*)d_in[0];
    const float* mask     = (const float*)d_in[1];
    const float* ln_in_g  = (const float*)d_in[2];
    const float* ln_in_b  = (const float*)d_in[3];
    const float* Wap      = (const float*)d_in[4];
    const float* bap      = (const float*)d_in[5];
    const float* Wbp      = (const float*)d_in[6];
    const float* bbp      = (const float*)d_in[7];
    const float* Wag      = (const float*)d_in[8];
    const float* bag      = (const float*)d_in[9];
    const float* Wbg      = (const float*)d_in[10];
    const float* bbg      = (const float*)d_in[11];
    const float* ln_out_g = (const float*)d_in[12];
    const float* ln_out_b = (const float*)d_in[13];
    const float* Wo       = (const float*)d_in[14];
    const float* bo       = (const float*)d_in[15];
    const float* Wg       = (const float*)d_in[16];
    const float* bg       = (const float*)d_in[17];

    u16* a_t = (u16*)d_ws;
    u16* b_t = a_t + (size_t)128 * NROW;
    u16* x_t = b_t + (size_t)128 * NROW;
    u16* wbf = x_t + (size_t)128 * NROW;         // 6 x 16384 bf16 weights
    float* scale = (float*)(wbf + 6 * 16384);    // byte offset is 16-aligned
    float* outf  = (float*)d_out;

    const u16* Wapb = wbf + 0 * 16384;
    const u16* Wagb = wbf + 1 * 16384;
    const u16* Wbpb = wbf + 2 * 16384;
    const u16* Wbgb = wbf + 3 * 16384;
    const u16* Wgb  = wbf + 4 * 16384;
    const u16* Wob  = wbf + 5 * 16384;

    k0_wconv<<<dim3(384), dim3(256), 0, stream>>>(Wap, Wag, Wbp, Wbg, Wg, Wo, wbf);
    k1_ln_proj<<<dim3(2064), dim3(256), 0, stream>>>(z, mask, ln_in_g, ln_in_b,
        Wapb, bap, Wagb, bag, Wbpb, bbp, Wbgb, bbg, a_t, b_t, scale, outf);
    k3_einsum<<<dim3(2048), dim3(256), 0, stream>>>(a_t, b_t, scale, x_t);
    k4_out<<<dim3(2048), dim3(256), 0, stream>>>(x_t, mask, ln_out_g, ln_out_b,
        Wob, bo, Wgb, bg, outf);
}

// Round 7
// 599.883 us; speedup vs baseline: 1.3378x; 1.0249x over previous
//
#include <hip/hip_runtime.h>
#include <stdint.h>

typedef unsigned short u16;
typedef __bf16 bf16x8 __attribute__((ext_vector_type(8)));
typedef float  f32x4 __attribute__((ext_vector_type(4)));
typedef u16    u16x8 __attribute__((ext_vector_type(8)));
typedef u16    u16x4 __attribute__((ext_vector_type(4)));

constexpr int LL = 512;
constexpr int NROW = LL * LL;   // 262144 flat rows (i*L+k or i*L+j)

__device__ __forceinline__ u16 f2b(float f) {
    __bf16 h = (__bf16)f;                 // RNE
    return __builtin_bit_cast(u16, h);
}
__device__ __forceinline__ float b2f(u16 s) {
    union { unsigned u; float f; } v; v.u = ((unsigned)s) << 16; return v.f;
}
__device__ __forceinline__ float sigmoidf_(float x) { return 1.0f / (1.0f + __expf(-x)); }

__device__ __forceinline__ f32x4 mfma16(bf16x8 a, bf16x8 b, f32x4 c) {
    return __builtin_amdgcn_mfma_f32_16x16x32_bf16(a, b, c, 0, 0, 0);
}

// direct HBM->LDS, 16B/lane; dest is wave-uniform base + lane*16 (linear)
__device__ __forceinline__ void glds16(const void* g, void* l) {
    __builtin_amdgcn_global_load_lds(
        (const __attribute__((address_space(1))) void*)g,
        (__attribute__((address_space(3))) void*)l, 16, 0, 0);
}

// ---------------- Kernel 0: weights f32 -> bf16 (one-time, tiny) ----------------
__global__ __launch_bounds__(256)
void k0_wconv(const float* __restrict__ Wap, const float* __restrict__ Wag,
              const float* __restrict__ Wbp, const float* __restrict__ Wbg,
              const float* __restrict__ Wg, const float* __restrict__ Wo,
              u16* __restrict__ wbf)
{
    const float* srcs[6] = {Wap, Wag, Wbp, Wbg, Wg, Wo};
    const int m = blockIdx.x >> 6;                       // 64 blocks per 16384-elem matrix
    const int e = ((blockIdx.x & 63) << 8) | threadIdx.x;
    wbf[m * 16384 + e] = f2b(srcs[m][e]);
}

// ---------------- Kernel 1 (fused): scale tiles (blocks 0..15) + LN(z)+projections ----
// LN: single global pass; z tile held in registers (16 x f32x4/thread) between the
// stats pass and the normalize pass (two-pass re-read missed L2 AND L3: 252MB fetch, r3).
// z_norm block region in d_out: u16 data based at (u16*)(zn_out + row0*128) (byte row0*512).
// (256,2): 128 arch + 128 acc = 256-reg budget exactly; (256,3)/(256,4) both spilled (r1/r2).
__global__ __launch_bounds__(256, 2)
void k1_ln_proj(const float* __restrict__ z, const float* __restrict__ mask,
                const float* __restrict__ lg, const float* __restrict__ lb,
                const u16* __restrict__ Wapb, const float* __restrict__ bap,
                const u16* __restrict__ Wagb, const float* __restrict__ bag,
                const u16* __restrict__ Wbpb, const float* __restrict__ bbp,
                const u16* __restrict__ Wbgb, const float* __restrict__ bbg,
                u16* __restrict__ a_t, u16* __restrict__ b_t,
                float* __restrict__ scale, float* zn_out)
{
    __shared__ __align__(16) u16 pool[18432];   // 36,864 B: max(LN path 36,352, scale path 36,864)

    const int tid = threadIdx.x;
    const int lane = tid & 63, wave = tid >> 6;
    const int wm = (wave >> 1) * 64, wn = (wave & 1) * 64;
    const int lr = lane & 15, quad = lane >> 4, kq = quad * 8;

    if (blockIdx.x < 16) {
        // ---- scale[i,j] = rsqrt(max(mask_i . mask_j, 1)) ; depends only on mask ----
        u16 (*As)[72] = (u16(*)[72])pool;
        u16 (*Bs)[72] = (u16(*)[72])(pool + 128 * 72);
        const int sb = blockIdx.x;
        const int i0 = (sb >> 2) * 128, j0 = (sb & 3) * 128;

        f32x4 acc[4][4];
#pragma unroll
        for (int i = 0; i < 4; ++i)
#pragma unroll
            for (int j = 0; j < 4; ++j) acc[i][j] = (f32x4){0.f, 0.f, 0.f, 0.f};

        for (int kc = 0; kc < LL; kc += 64) {
#pragma unroll
            for (int p = 0; p < 8; ++p) {
                const int q = p * 256 + tid, rr = q >> 4, ko = (q & 15) * 4;
                f32x4 va = *(const f32x4*)(mask + (size_t)(i0 + rr) * LL + kc + ko);
                f32x4 vb = *(const f32x4*)(mask + (size_t)(j0 + rr) * LL + kc + ko);
                u16x4 ca, cb;
#pragma unroll
                for (int e = 0; e < 4; ++e) { ca[e] = f2b(va[e]); cb[e] = f2b(vb[e]); }
                *(u16x4*)&As[rr][ko] = ca;
                *(u16x4*)&Bs[rr][ko] = cb;
            }
            __syncthreads();
#pragma unroll
            for (int kk = 0; kk < 64; kk += 32) {
                bf16x8 af[4], bf[4];
#pragma unroll
                for (int mt = 0; mt < 4; ++mt) af[mt] = *(const bf16x8*)&As[wm + mt * 16 + lr][kk + kq];
#pragma unroll
                for (int nt = 0; nt < 4; ++nt) bf[nt] = *(const bf16x8*)&Bs[wn + nt * 16 + lr][kk + kq];
#pragma unroll
                for (int mt = 0; mt < 4; ++mt)
#pragma unroll
                    for (int nt = 0; nt < 4; ++nt) acc[mt][nt] = mfma16(af[mt], bf[nt], acc[mt][nt]);
            }
            __syncthreads();
        }
#pragma unroll
        for (int mt = 0; mt < 4; ++mt)
#pragma unroll
            for (int nt = 0; nt < 4; ++nt) {
                const int gj = j0 + wn + nt * 16 + lr;
#pragma unroll
                for (int e = 0; e < 4; ++e) {
                    const int gi = i0 + wm + mt * 16 + quad * 4 + e;
                    scale[(size_t)gi * LL + gj] = rsqrtf(fmaxf(acc[mt][nt][e], 1.0f));
                }
            }
        return;
    }

    // ---- LN + projections path ----
    u16 (*Zs)[136] = (u16(*)[136])pool;         // 17,408 u16 = 34,816 B
    float* Gg = (float*)(pool + 17408);         // +512 B
    float* Gb = Gg + 128;                       // +512 B
    float* Ms = Gb + 128;                       // +512 B  (total 36,352 B)

    const int row0 = (blockIdx.x - 16) * 128;

    if (tid < 128) { Gg[tid] = lg[tid]; Gb[tid] = lb[tid]; Ms[tid] = mask[row0 + tid]; }

    // LN phase: pair (2r,2r+1) owns row r; halves h=0/64. Single global pass:
    // z half-row lives in 16 f32x4 registers (phase-local; acc regs not yet live).
    {
        const int r = tid >> 1, h = (tid & 1) * 64;
        const float* zrow = z + (size_t)(row0 + r) * 128 + h;
        f32x4 zv[16];
        float s1 = 0.f, s2 = 0.f;
#pragma unroll
        for (int j = 0; j < 16; ++j) {
            zv[j] = *(const f32x4*)(zrow + j * 4);
#pragma unroll
            for (int e = 0; e < 4; ++e) { s1 += zv[j][e]; s2 += zv[j][e] * zv[j][e]; }
        }
        s1 += __shfl_xor(s1, 1);
        s2 += __shfl_xor(s2, 1);
        const float mu = s1 * 0.0078125f;
        const float rs = rsqrtf(fmaxf(s2 * 0.0078125f - mu * mu, 0.f) + 1e-5f);
        __syncthreads();  // Gg/Gb ready
        // block-region base: u16 view of (zn_out + row0*128), then row r, half h
        u16* znb = (u16*)(zn_out + (size_t)row0 * 128) + r * 128 + h;
#pragma unroll
        for (int j = 0; j < 16; ++j) {
            u16x4 o;
#pragma unroll
            for (int e = 0; e < 4; ++e)
                o[e] = f2b((zv[j][e] - mu) * rs * Gg[h + j * 4 + e] + Gb[h + j * 4 + e]);
            *(u16x4*)&Zs[r][h + j * 4] = o;
            *(u16x4*)(znb + j * 4) = o;   // z_norm bf16 -> d_out block-region (k4 gate GEMM)
        }
    }
    __syncthreads();

    // a/b projections: P * sigmoid(G), masked, bf16 channel-major out
#pragma unroll 1
    for (int pair = 0; pair < 2; ++pair) {
        const u16* WP = pair ? Wbpb : Wapb;
        const float* BP = pair ? bbp : bap;
        const u16* WG = pair ? Wbgb : Wagb;
        const float* BG = pair ? bbg : bag;
        u16* outp = pair ? b_t : a_t;

        f32x4 accP[4][4], accG[4][4];
#pragma unroll
        for (int i = 0; i < 4; ++i)
#pragma unroll
            for (int j = 0; j < 4; ++j) {
                accP[i][j] = (f32x4){0.f, 0.f, 0.f, 0.f};
                accG[i][j] = (f32x4){0.f, 0.f, 0.f, 0.f};
            }
#pragma unroll
        for (int kk = 0; kk < 128; kk += 32) {
            bf16x8 af[4];
#pragma unroll
            for (int mt = 0; mt < 4; ++mt)
                af[mt] = *(const bf16x8*)&Zs[wm + mt * 16 + lr][kk + kq];
#pragma unroll
            for (int nt = 0; nt < 4; ++nt) {
                const int ncol = wn + nt * 16 + lr;
                bf16x8 bp8 = *(const bf16x8*)(WP + ncol * 128 + kk + kq);
                bf16x8 bg8 = *(const bf16x8*)(WG + ncol * 128 + kk + kq);
#pragma unroll
                for (int mt = 0; mt < 4; ++mt) {
                    accP[mt][nt] = mfma16(af[mt], bp8, accP[mt][nt]);
                    accG[mt][nt] = mfma16(af[mt], bg8, accG[mt][nt]);
                }
            }
        }
        // C/D layout: col=lane&15 (=ncol), row=quad*4+e -> rows contiguous in [c][row]
#pragma unroll
        for (int nt = 0; nt < 4; ++nt) {
            const int ncol = wn + nt * 16 + lr;
            const float bP = BP[ncol];
            const float bG = BG[ncol];
#pragma unroll
            for (int mt = 0; mt < 4; ++mt) {
                const int rb = wm + mt * 16 + quad * 4;
                u16x4 o;
#pragma unroll
                for (int e = 0; e < 4; ++e)
                    o[e] = f2b((accP[mt][nt][e] + bP) * sigmoidf_(accG[mt][nt][e] + bG) * Ms[rb + e]);
                *(u16x4*)(outp + (size_t)ncol * NROW + row0 + rb) = o;
            }
        }
    }
}

// ---------------- Kernel 3: triangle einsum, per-channel C = A.B^T ----------------
// grid 2048 = 8 XCDs x (16 channels x 16 tiles); a channel's 16 tiles share one XCD's L2.
// m97-style staging: global_load_lds width=16 into LINEAR As/Bs[128][64] (no VGPR
// roundtrip, no ds_writes). Linear stride 128B is row-bank-aliased, so XOR-swizzle
// BOTH sides (rule 21): source granule ^= row&7 at stage, read granule ^= R&7.
// BK=64 restored (BK=128 regressed ~+23us, r5). LDS 32KB.
__global__ __launch_bounds__(256, 2)
void k3_einsum(const u16* __restrict__ a_t, const u16* __restrict__ b_t,
               const float* __restrict__ scale, u16* __restrict__ x_t)
{
    __shared__ __align__(16) u16 pool[16384];  // As[128][64] | Bs[128][64]; reused as Ss[128][128]
    u16 (*Ss)[128] = (u16(*)[128])pool;

    const int bid = blockIdx.x;
    const int xcd = bid & 7, slot = bid >> 3;
    const int c = xcd * 16 + (slot >> 4);
    const int tile = slot & 15;
    const int i0 = (tile >> 2) * 128, j0 = (tile & 3) * 128;

    const u16* A = a_t + (size_t)c * NROW;
    const u16* B = b_t + (size_t)c * NROW;

    const int tid = threadIdx.x;
    const int lane = tid & 63, wave = tid >> 6;
    const int wm = (wave >> 1) * 64, wn = (wave & 1) * 64;
    const int lr = lane & 15, quad = lane >> 4;

    // staging: lane -> (row-in-chunk, inverse-swizzled source granule)
    const int rsub = lane >> 3;            // 0..7
    const int gsrc = (lane & 7) ^ rsub;    // granule to FETCH so linear dest = swizzled layout
    const char* Abase = (const char*)pool;
    const char* Bbase = (const char*)pool + 16384;
    const int sw0 = quad ^ (lr & 7);       // swizzled read granule for kk=0 (kk=32: ^4)

    f32x4 acc[4][4];
#pragma unroll
    for (int i = 0; i < 4; ++i)
#pragma unroll
        for (int j = 0; j < 4; ++j) acc[i][j] = (f32x4){0.f, 0.f, 0.f, 0.f};

    for (int kc = 0; kc < LL; kc += 64) {
#pragma unroll
        for (int i = 0; i < 4; ++i) {
            const int chunk = wave * 4 + i;          // wave-uniform
            const int r = chunk * 8 + rsub;
            glds16(A + (size_t)(i0 + r) * LL + kc + gsrc * 8, pool + chunk * 512);
            glds16(B + (size_t)(j0 + r) * LL + kc + gsrc * 8, pool + 8192 + chunk * 512);
        }
        __syncthreads();   // compiler drains vmcnt before barrier
#pragma unroll
        for (int kk = 0; kk < 64; kk += 32) {
            const int swg = sw0 ^ (kk >> 3);         // kk=0 -> sw0, kk=32 -> sw0^4
            bf16x8 af[4], bf[4];
#pragma unroll
            for (int mt = 0; mt < 4; ++mt) {
                const int R = wm + mt * 16 + lr;
                af[mt] = *(const bf16x8*)(Abase + R * 128 + (swg << 4));
            }
#pragma unroll
            for (int nt = 0; nt < 4; ++nt) {
                const int R = wn + nt * 16 + lr;
                bf[nt] = *(const bf16x8*)(Bbase + R * 128 + (swg << 4));
            }
#pragma unroll
            for (int mt = 0; mt < 4; ++mt)
#pragma unroll
                for (int nt = 0; nt < 4; ++nt) acc[mt][nt] = mfma16(af[mt], bf[nt], acc[mt][nt]);
        }
        __syncthreads();  // also guards pool reuse below on last iteration
    }
    // epilogue: x = acc * scale[i,j] -> bf16, stash (pool reuse) then coalesced store
#pragma unroll
    for (int mt = 0; mt < 4; ++mt)
#pragma unroll
        for (int nt = 0; nt < 4; ++nt) {
            const int cc = wn + nt * 16 + lr;
#pragma unroll
            for (int e = 0; e < 4; ++e) {
                const int rr = wm + mt * 16 + quad * 4 + e;
                const float s = scale[(size_t)(i0 + rr) * LL + j0 + cc];
                Ss[rr][cc] = f2b(acc[mt][nt][e] * s);
            }
        }
    __syncthreads();
#pragma unroll
    for (int p = 0; p < 8; ++p) {
        const int rr = p * 16 + (tid >> 4);
        const int jo = (tid & 15) * 8;
        *(u16x8*)(x_t + (size_t)c * NROW + (size_t)(i0 + rr) * LL + j0 + jo) = *(const u16x8*)&Ss[rr][jo];
    }
}

// ---------------- Kernel 4: LN(x) @ Wo^T + bo, * sigmoid(z_norm @ Wg^T + bg) * mask ----
// z_norm bf16 staged from out's own block-region (written by k1) BEFORE any out write.
// nh-split keeps live accumulators at 64 (peak ~154 unified regs, safe at (256,2)).
__global__ __launch_bounds__(256, 2)
void k4_out(const u16* __restrict__ x_t, const float* __restrict__ mask,
            const float* __restrict__ lg, const float* __restrict__ lb,
            const u16* __restrict__ Wob, const float* __restrict__ bo,
            const u16* __restrict__ Wgb, const float* __restrict__ bgv,
            float* out)
{
    __shared__ __align__(16) u16 Zs[128][136];  // x_norm bf16 tile
    __shared__ __align__(16) u16 Zn[128][136];  // z_norm bf16 tile
    __shared__ float Ms[128];

    const int tid = threadIdx.x;
    const int row0 = blockIdx.x * 128;

    if (tid < 128) Ms[tid] = mask[row0 + tid];

    {   // stage z_norm from out's block-region (must complete before out writes; it does:
        // all reads here, all writes in the final epilogue after __syncthreads)
        const u16* znb = (const u16*)(out + (size_t)row0 * 128);
#pragma unroll
        for (int p = 0; p < 8; ++p) {
            const int idx = p * 256 + tid;
            const int rr = idx >> 4, co = (idx & 15) * 8;
            *(u16x8*)&Zn[rr][co] = *(const u16x8*)(znb + rr * 128 + co);
        }
    }

    {   // transpose-stage x_t[c][ij] -> Zs[ij][c] via in-register 4x4 transpose
        const int ijo = (tid & 31) * 4;
        const int cb = (tid >> 5) * 4;
#pragma unroll
        for (int p = 0; p < 4; ++p) {
            const int c = p * 32 + cb;
            u16x4 v0 = *(const u16x4*)(x_t + (size_t)(c + 0) * NROW + row0 + ijo);
            u16x4 v1 = *(const u16x4*)(x_t + (size_t)(c + 1) * NROW + row0 + ijo);
            u16x4 v2 = *(const u16x4*)(x_t + (size_t)(c + 2) * NROW + row0 + ijo);
            u16x4 v3 = *(const u16x4*)(x_t + (size_t)(c + 3) * NROW + row0 + ijo);
#pragma unroll
            for (int i = 0; i < 4; ++i) {
                u16x4 w = { v0[i], v1[i], v2[i], v3[i] };
                *(u16x4*)&Zs[ijo + i][c] = w;
            }
        }
    }
    __syncthreads();

    // in-place LN over rows of Zs (bf16 -> f32 stats -> bf16)
    {
        const int r = tid >> 1, h = (tid & 1) * 64;
        float s1 = 0.f, s2 = 0.f;
#pragma unroll
        for (int j = 0; j < 64; j += 8) {
            u16x8 v = *(const u16x8*)&Zs[r][h + j];
#pragma unroll
            for (int e = 0; e < 8; ++e) { float x = b2f(v[e]); s1 += x; s2 += x * x; }
        }
        s1 += __shfl_xor(s1, 1);
        s2 += __shfl_xor(s2, 1);
        const float mu = s1 * 0.0078125f;
        const float rs = rsqrtf(fmaxf(s2 * 0.0078125f - mu * mu, 0.f) + 1e-5f);
#pragma unroll
        for (int j = 0; j < 64; j += 8) {
            const int c = h + j;
            u16x8 v = *(const u16x8*)&Zs[r][c];
            u16x8 o;
#pragma unroll
            for (int e = 0; e < 8; ++e)
                o[e] = f2b((b2f(v[e]) - mu) * rs * lg[c + e] + lb[c + e]);
            *(u16x8*)&Zs[r][c] = o;
        }
    }
    __syncthreads();

    const int lane = tid & 63, wave = tid >> 6;
    const int wm = (wave >> 1) * 64, wn = (wave & 1) * 64;
    const int lr = lane & 15, quad = lane >> 4, kq = quad * 8;

#pragma unroll 1
    for (int nh = 0; nh < 2; ++nh) {
        f32x4 accO[4][2], accG[4][2];
#pragma unroll
        for (int i = 0; i < 4; ++i)
#pragma unroll
            for (int j = 0; j < 2; ++j) {
                accO[i][j] = (f32x4){0.f, 0.f, 0.f, 0.f};
                accG[i][j] = (f32x4){0.f, 0.f, 0.f, 0.f};
            }
#pragma unroll
        for (int kk = 0; kk < 128; kk += 32) {
            bf16x8 ax[4], az[4];
#pragma unroll
            for (int mt = 0; mt < 4; ++mt) {
                ax[mt] = *(const bf16x8*)&Zs[wm + mt * 16 + lr][kk + kq];
                az[mt] = *(const bf16x8*)&Zn[wm + mt * 16 + lr][kk + kq];
            }
#pragma unroll
            for (int n2 = 0; n2 < 2; ++n2) {
                const int ncol = wn + (nh * 2 + n2) * 16 + lr;
                bf16x8 bo8 = *(const bf16x8*)(Wob + ncol * 128 + kk + kq);
                bf16x8 bg8 = *(const bf16x8*)(Wgb + ncol * 128 + kk + kq);
#pragma unroll
                for (int mt = 0; mt < 4; ++mt) {
                    accO[mt][n2] = mfma16(ax[mt], bo8, accO[mt][n2]);
                    accG[mt][n2] = mfma16(az[mt], bg8, accG[mt][n2]);
                }
            }
        }
#pragma unroll
        for (int n2 = 0; n2 < 2; ++n2) {
            const int cc = wn + (nh * 2 + n2) * 16 + lr;
            const float bb = bo[cc];
            const float bg = bgv[cc];
#pragma unroll
            for (int mt = 0; mt < 4; ++mt) {
                const int rb = wm + mt * 16 + quad * 4;
#pragma unroll
                for (int e = 0; e < 4; ++e) {
                    const size_t idx = (size_t)(row0 + rb + e) * 128 + cc;
                    out[idx] = (accO[mt][n2][e] + bb) * sigmoidf_(accG[mt][n2][e] + bg) * Ms[rb + e];
                }
            }
        }
    }
}

// ---------------- launcher ----------------
// ws: a_t 64MiB + b_t 64MiB + x_t 64MiB + wbf 192KiB + scale 1MiB ~= 193.2 MiB.
// z_norm bf16 lives in d_out (each block's own 32KB of its 64KB f32 region); k4
// stages it to LDS before overwriting with the final output.
extern "C" void kernel_launch(void* const* d_in, const int* in_sizes, int n_in,
                              void* d_out, int out_size, void* d_ws, size_t ws_size,
                              hipStream_t stream)
{
    const float* z        = (const float*)d_in[0];
    const float* mask     = (const float*)d_in[1];
    const float* ln_in_g  = (const float*)d_in[2];
    const float* ln_in_b  = (const float*)d_in[3];
    const float* Wap      = (const float*)d_in[4];
    const float* bap      = (const float*)d_in[5];
    const float* Wbp      = (const float*)d_in[6];
    const float* bbp      = (const float*)d_in[7];
    const float* Wag      = (const float*)d_in[8];
    const float* bag      = (const float*)d_in[9];
    const float* Wbg      = (const float*)d_in[10];
    const float* bbg      = (const float*)d_in[11];
    const float* ln_out_g = (const float*)d_in[12];
    const float* ln_out_b = (const float*)d_in[13];
    const float* Wo       = (const float*)d_in[14];
    const float* bo       = (const float*)d_in[15];
    const float* Wg       = (const float*)d_in[16];
    const float* bg       = (const float*)d_in[17];

    u16* a_t = (u16*)d_ws;
    u16* b_t = a_t + (size_t)128 * NROW;
    u16* x_t = b_t + (size_t)128 * NROW;
    u16* wbf = x_t + (size_t)128 * NROW;         // 6 x 16384 bf16 weights
    float* scale = (float*)(wbf + 6 * 16384);    // byte offset is 16-aligned
    float* outf  = (float*)d_out;

    const u16* Wapb = wbf + 0 * 16384;
    const u16* Wagb = wbf + 1 * 16384;
    const u16* Wbpb = wbf + 2 * 16384;
    const u16* Wbgb = wbf + 3 * 16384;
    const u16* Wgb  = wbf + 4 * 16384;
    const u16* Wob  = wbf + 5 * 16384;

    k0_wconv<<<dim3(384), dim3(256), 0, stream>>>(Wap, Wag, Wbp, Wbg, Wg, Wo, wbf);
    k1_ln_proj<<<dim3(2064), dim3(256), 0, stream>>>(z, mask, ln_in_g, ln_in_b,
        Wapb, bap, Wagb, bag, Wbpb, bbp, Wbgb, bbg, a_t, b_t, scale, outf);
    k3_einsum<<<dim3(2048), dim3(256), 0, stream>>>(a_t, b_t, scale, x_t);
    k4_out<<<dim3(2048), dim3(256), 0, stream>>>(x_t, mask, ln_out_g, ln_out_b,
        Wob, bo, Wgb, bg, outf);
}